// Round 4
// baseline (2736.009 us; speedup 1.0000x reference)
//
#include <hip/hip_runtime.h>
#include <math.h>
#include <stdint.h>

#define B_ 4
#define S_ 1024
#define E_ 768
#define H_ 3072
#define V_ 16384
#define L_ 5
#define T_TOK 4096   // B_*S_

typedef unsigned short u16;
typedef short bf16x8 __attribute__((ext_vector_type(8)));
typedef float floatx4 __attribute__((ext_vector_type(4)));
typedef u16 u16x4 __attribute__((ext_vector_type(4)));

__device__ __forceinline__ u16 f2bf(float f) {
    union { float f; unsigned u; } x; x.f = f;
    unsigned r = (x.u + 0x7FFFu + ((x.u >> 16) & 1u)) >> 16;
    return (u16)r;
}
__device__ __forceinline__ float bf2f(u16 v) {
    union { unsigned u; float f; } x; x.u = ((unsigned)v) << 16;
    return x.f;
}

__device__ __forceinline__ void gload16(const void* g, void* l) {
    __builtin_amdgcn_global_load_lds(
        (const __attribute__((address_space(1))) unsigned int*)(uintptr_t)g,
        (__attribute__((address_space(3))) unsigned int*)(uintptr_t)l,
        16, 0, 0);
}

__device__ __forceinline__ void bar_sync() {
    asm volatile("s_waitcnt vmcnt(0)" ::: "memory");
    __builtin_amdgcn_s_barrier();
    asm volatile("" ::: "memory");
}

// ---------------------------------------------------------------------------
// 128x128 2-phase kernel (kept for small-N / attention GEMMs).
#define BM 128
#define BN 128
#define BK 32

template<int OBF, int RELU, int BIAS>
__global__ __launch_bounds__(256) void mgemm(
    const u16* __restrict__ A, const u16* __restrict__ B, void* __restrict__ Cv,
    const float* __restrict__ bias, float alpha, int M, int N, int K,
    int lda, int ldb, int ldc,
    long sA, long sB, long sC)
{
    __shared__ u16 As[2][BM * BK];
    __shared__ u16 Bs[2][BN * BK];

    const int tid  = threadIdx.x;
    const int lane = tid & 63;
    const int wid  = tid >> 6;
    const int wr   = (wid >> 1) * 64;
    const int wc   = (wid & 1) * 64;
    const int lr   = lane & 15;
    const int kg   = lane >> 4;

    const long rowBase = (long)blockIdx.y * BM;
    const long colBase = (long)blockIdx.x * BN;

    const u16* Ab = A + (long)blockIdx.z * sA;
    const u16* Bb = B + (long)blockIdx.z * sB;

    const int c0 = tid, c1 = tid + 256;
    const int ar0 = c0 >> 2, ac0 = (c0 & 3) ^ ((ar0 >> 1) & 3);
    const int ar1 = c1 >> 2, ac1 = (c1 & 3) ^ ((ar1 >> 1) & 3);

    const u16* pa0 = Ab + (rowBase + ar0) * (long)lda + ac0 * 8;
    const u16* pa1 = Ab + (rowBase + ar1) * (long)lda + ac1 * 8;
    const u16* pb0 = Bb + (colBase + ar0) * (long)ldb + ac0 * 8;
    const u16* pb1 = Bb + (colBase + ar1) * (long)ldb + ac1 * 8;

    int aoff[4], boff[4];
    #pragma unroll
    for (int m = 0; m < 4; ++m) {
        int r = wr + m * 16 + lr;
        aoff[m] = r * 32 + ((kg ^ ((r >> 1) & 3)) << 3);
        int c = wc + m * 16 + lr;
        boff[m] = c * 32 + ((kg ^ ((c >> 1) & 3)) << 3);
    }

    floatx4 acc[4][4];
    #pragma unroll
    for (int m = 0; m < 4; ++m)
        #pragma unroll
        for (int n = 0; n < 4; ++n)
            acc[m][n] = (floatx4)0.f;

    auto stage = [&](int buf, int k0) {
        gload16(pa0 + k0, &As[buf][c0 * 8]);
        gload16(pa1 + k0, &As[buf][c1 * 8]);
        gload16(pb0 + k0, &Bs[buf][c0 * 8]);
        gload16(pb1 + k0, &Bs[buf][c1 * 8]);
    };

    const int NT = K / BK;
    stage(0, 0);
    bar_sync();

    for (int t = 0; t < NT; ++t) {
        const int cur = t & 1;
        if (t + 1 < NT) stage(cur ^ 1, (t + 1) * BK);

        bf16x8 af[4], bfr[4];
        #pragma unroll
        for (int m = 0; m < 4; ++m) af[m]  = *(const bf16x8*)(&As[cur][aoff[m]]);
        #pragma unroll
        for (int n = 0; n < 4; ++n) bfr[n] = *(const bf16x8*)(&Bs[cur][boff[n]]);
        #pragma unroll
        for (int m = 0; m < 4; ++m)
            #pragma unroll
            for (int n = 0; n < 4; ++n)
                acc[m][n] = __builtin_amdgcn_mfma_f32_16x16x32_bf16(
                                af[m], bfr[n], acc[m][n], 0, 0, 0);

        if (t + 1 < NT) bar_sync();
    }

    const long col0 = colBase + wc + lr;
    const long row0 = rowBase + wr + kg * 4;
    if (OBF) {
        u16* C = (u16*)Cv + (long)blockIdx.z * sC;
        #pragma unroll
        for (int n = 0; n < 4; ++n) {
            long col = col0 + n * 16;
            float bv = BIAS ? bias[col] : 0.f;
            #pragma unroll
            for (int m = 0; m < 4; ++m)
                #pragma unroll
                for (int j = 0; j < 4; ++j) {
                    float v = acc[m][n][j] * alpha + bv;
                    if (RELU) v = fmaxf(v, 0.f);
                    C[(row0 + m * 16 + j) * (long)ldc + col] = f2bf(v);
                }
        }
    } else {
        float* C = (float*)Cv + (long)blockIdx.z * sC;
        #pragma unroll
        for (int n = 0; n < 4; ++n) {
            long col = col0 + n * 16;
            float bv = BIAS ? bias[col] : 0.f;
            #pragma unroll
            for (int m = 0; m < 4; ++m)
                #pragma unroll
                for (int j = 0; j < 4; ++j) {
                    float v = acc[m][n][j] * alpha + bv;
                    if (RELU) v = fmaxf(v, 0.f);
                    C[(row0 + m * 16 + j) * (long)ldc + col] = v;
                }
        }
    }
}

// ---------------------------------------------------------------------------
// 256x256 8-wave phase-split pipelined GEMM (T3+T4+T5), triple-buffered LDS,
// BK=32, counted vmcnt(4) — loads stay in flight across barriers.
template<int OBF, int RELU, int BIAS>
__global__ __launch_bounds__(512, 2) void mgemm8(
    const u16* __restrict__ A, const u16* __restrict__ B, void* __restrict__ Cv,
    const float* __restrict__ bias, float alpha, int M, int N, int K,
    int lda, int ldb, int ldc)
{
    __shared__ u16 As[3][256 * 32];   // 48 KB
    __shared__ u16 Bs[3][256 * 32];   // 48 KB

    const int tid  = threadIdx.x;
    const int lane = tid & 63;
    const int wid  = tid >> 6;
    const int wm   = wid >> 2;        // 0..1  (M half)
    const int wn   = wid & 3;         // 0..3  (N quarter)
    const int lr   = lane & 15;
    const int kg   = lane >> 4;

    const long rowBase = (long)blockIdx.y * 256;
    const long colBase = (long)blockIdx.x * 256;

    // staging: 1024 16B-chunks per operand tile; thread covers c0=tid, c1=tid+512
    const int c0 = tid, c1 = tid + 512;
    const int r0 = c0 >> 2, ch0 = (c0 & 3) ^ ((r0 >> 1) & 3);
    const int r1 = c1 >> 2, ch1 = (c1 & 3) ^ ((r1 >> 1) & 3);

    const u16* pa0 = A + (rowBase + r0) * (long)lda + ch0 * 8;
    const u16* pa1 = A + (rowBase + r1) * (long)lda + ch1 * 8;
    const u16* pb0 = B + (colBase + r0) * (long)ldb + ch0 * 8;
    const u16* pb1 = B + (colBase + r1) * (long)ldb + ch1 * 8;

    int aoff[8], boff[4];
    #pragma unroll
    for (int mi = 0; mi < 8; ++mi) {
        int r = wm * 128 + mi * 16 + lr;
        aoff[mi] = r * 32 + ((kg ^ ((r >> 1) & 3)) << 3);
    }
    #pragma unroll
    for (int ni = 0; ni < 4; ++ni) {
        int c = wn * 64 + ni * 16 + lr;
        boff[ni] = c * 32 + ((kg ^ ((c >> 1) & 3)) << 3);
    }

    floatx4 acc[8][4];
    #pragma unroll
    for (int mi = 0; mi < 8; ++mi)
        #pragma unroll
        for (int ni = 0; ni < 4; ++ni)
            acc[mi][ni] = (floatx4)0.f;

    auto stageA = [&](int buf, int kt) {
        gload16(pa0 + (long)kt * BK, &As[buf][c0 * 8]);
        gload16(pa1 + (long)kt * BK, &As[buf][c1 * 8]);
    };
    auto stageB = [&](int buf, int kt) {
        gload16(pb0 + (long)kt * BK, &Bs[buf][c0 * 8]);
        gload16(pb1 + (long)kt * BK, &Bs[buf][c1 * 8]);
    };

    const int NT = K / 32;
    // prologue: tiles 0,1
    stageA(0, 0); stageB(0, 0);
    stageA(1, 1); stageB(1, 1);
    asm volatile("s_waitcnt vmcnt(4)" ::: "memory");   // tile 0 landed
    __builtin_amdgcn_sched_barrier(0);
    __builtin_amdgcn_s_barrier();

    int b0 = 0, b1 = 1, b2 = 2;
    for (int t = 0; t < NT; ++t) {
        bf16x8 afr[4], bfr[4];
        // ---------------- phase A: quadrant mh=0 ----------------
        if (t + 2 < NT) stageA(b2, t + 2);
        #pragma unroll
        for (int mi = 0; mi < 4; ++mi) afr[mi] = *(const bf16x8*)(&As[b0][aoff[mi]]);
        #pragma unroll
        for (int ni = 0; ni < 4; ++ni) bfr[ni] = *(const bf16x8*)(&Bs[b0][boff[ni]]);
        __builtin_amdgcn_s_barrier();
        asm volatile("s_waitcnt lgkmcnt(0)" ::: "memory");
        __builtin_amdgcn_sched_barrier(0);
        __builtin_amdgcn_s_setprio(1);
        #pragma unroll
        for (int mi = 0; mi < 4; ++mi)
            #pragma unroll
            for (int ni = 0; ni < 4; ++ni)
                acc[mi][ni] = __builtin_amdgcn_mfma_f32_16x16x32_bf16(
                                  afr[mi], bfr[ni], acc[mi][ni], 0, 0, 0);
        __builtin_amdgcn_s_setprio(0);
        __builtin_amdgcn_sched_barrier(0);
        __builtin_amdgcn_s_barrier();
        // ---------------- phase B: quadrant mh=1 ----------------
        if (t + 2 < NT) stageB(b2, t + 2);
        #pragma unroll
        for (int mi = 0; mi < 4; ++mi) afr[mi] = *(const bf16x8*)(&As[b0][aoff[4 + mi]]);
        __builtin_amdgcn_s_barrier();
        asm volatile("s_waitcnt lgkmcnt(0)" ::: "memory");
        __builtin_amdgcn_sched_barrier(0);
        __builtin_amdgcn_s_setprio(1);
        #pragma unroll
        for (int mi = 0; mi < 4; ++mi)
            #pragma unroll
            for (int ni = 0; ni < 4; ++ni)
                acc[4 + mi][ni] = __builtin_amdgcn_mfma_f32_16x16x32_bf16(
                                      afr[mi], bfr[ni], acc[4 + mi][ni], 0, 0, 0);
        __builtin_amdgcn_s_setprio(0);
        __builtin_amdgcn_sched_barrier(0);
        if (t + 2 < NT) { asm volatile("s_waitcnt vmcnt(4)" ::: "memory"); }
        else            { asm volatile("s_waitcnt vmcnt(0)" ::: "memory"); }
        __builtin_amdgcn_sched_barrier(0);
        __builtin_amdgcn_s_barrier();
        int tb = b0; b0 = b1; b1 = b2; b2 = tb;
    }

    // epilogue
    const long col0 = colBase + wn * 64 + lr;
    const long row0 = rowBase + wm * 128 + kg * 4;
    if (OBF) {
        u16* C = (u16*)Cv;
        #pragma unroll
        for (int ni = 0; ni < 4; ++ni) {
            long col = col0 + ni * 16;
            float bv = BIAS ? bias[col] : 0.f;
            #pragma unroll
            for (int mi = 0; mi < 8; ++mi)
                #pragma unroll
                for (int j = 0; j < 4; ++j) {
                    float v = acc[mi][ni][j] * alpha + bv;
                    if (RELU) v = fmaxf(v, 0.f);
                    C[(row0 + mi * 16 + j) * (long)ldc + col] = f2bf(v);
                }
        }
    } else {
        float* C = (float*)Cv;
        #pragma unroll
        for (int ni = 0; ni < 4; ++ni) {
            long col = col0 + ni * 16;
            float bv = BIAS ? bias[col] : 0.f;
            #pragma unroll
            for (int mi = 0; mi < 8; ++mi)
                #pragma unroll
                for (int j = 0; j < 4; ++j) {
                    float v = acc[mi][ni][j] * alpha + bv;
                    if (RELU) v = fmaxf(v, 0.f);
                    C[(row0 + mi * 16 + j) * (long)ldc + col] = v;
                }
        }
    }
}

// ---------------------------------------------------------------------------
__device__ __forceinline__ u16 cvt_elem(float f) { return f2bf(f); }
__device__ __forceinline__ u16 cvt_elem(u16 v)   { return v; }

template<typename TI>
__global__ __launch_bounds__(256) void tcvt(
    const TI* __restrict__ in, u16* __restrict__ out,
    int ldIn, int ldOut, long sIn, long sOut)
{
    __shared__ u16 t[32][33];
    const int tx = threadIdx.x & 31, ty = threadIdx.x >> 5;
    const long r0 = (long)blockIdx.y * 32, c0 = (long)blockIdx.x * 32;
    const TI* ib = in + (long)blockIdx.z * sIn;
    u16* ob = out + (long)blockIdx.z * sOut;
    #pragma unroll
    for (int j = 0; j < 4; ++j) {
        int r = ty + j * 8;
        t[r][tx] = cvt_elem(ib[(r0 + r) * (long)ldIn + c0 + tx]);
    }
    __syncthreads();
    #pragma unroll
    for (int j = 0; j < 4; ++j) {
        int c = ty + j * 8;
        ob[(c0 + c) * (long)ldOut + r0 + tx] = t[tx][c];
    }
}

// ---------------------------------------------------------------------------
__global__ __launch_bounds__(256) void gather_kernel(
    const int* __restrict__ seq, const float* __restrict__ embed,
    float* __restrict__ f_emb, float* __restrict__ f_x, u16* __restrict__ xb)
{
    int t = blockIdx.x;
    int tok = seq[t];
    const float* src = embed + (long)tok * E_;
    long base = (long)t * E_;
    #pragma unroll
    for (int j = 0; j < 3; ++j) {
        int i = threadIdx.x + j * 256;
        float v = src[i];
        f_emb[base + i] = v;
        f_x[base + i] = v;
        xb[base + i] = f2bf(v);
    }
}

__global__ __launch_bounds__(256) void seed_kernel(
    const float4* __restrict__ src, float4* __restrict__ x,
    u16* __restrict__ xb, long n4)
{
    long i = (long)blockIdx.x * blockDim.x + threadIdx.x;
    long stride = (long)gridDim.x * blockDim.x;
    for (; i < n4; i += stride) {
        float4 v = src[i];
        x[i] = v;
        u16x4 b = { f2bf(v.x), f2bf(v.y), f2bf(v.z), f2bf(v.w) };
        *(u16x4*)(xb + i * 4) = b;
    }
}

// ---------------------------------------------------------------------------
// RoPE cos/sin table: tab[s][i] = (cos, sin) of s * 10000^(-2i/E)
__global__ __launch_bounds__(384) void rope_tab_kernel(float2* __restrict__ tab)
{
    int s = blockIdx.x;
    int i = threadIdx.x;
    float inv = expf(-(float)(2 * i) * (9.210340371976184f / (float)E_));
    float ang = (float)s * inv;
    float sn, cs;
    sincosf(ang, &sn, &cs);
    tab[(long)s * 384 + i] = make_float2(cs, sn);
}

// RoPE in-place on fused bf16 QKV [T][2304]: q at col 0, k at 768.
__global__ __launch_bounds__(384) void rope_kernel(
    u16* __restrict__ qkv, const float2* __restrict__ tab)
{
    int t = blockIdx.x;
    int i = threadIdx.x;
    int s = t & (S_ - 1);
    float2 f = tab[(long)s * 384 + i];
    float cs = f.x, sn = f.y;
    u16* base = qkv + (long)t * 2304;

    unsigned vq = *(unsigned*)(base + 2 * i);
    unsigned vk = *(unsigned*)(base + 768 + 2 * i);
    float qx = bf2f((u16)(vq & 0xffff)), qy = bf2f((u16)(vq >> 16));
    float kx = bf2f((u16)(vk & 0xffff)), ky = bf2f((u16)(vk >> 16));
    unsigned pq = (unsigned)f2bf(qx * cs - qy * sn) |
                  ((unsigned)f2bf(qx * sn + qy * cs) << 16);
    unsigned pk = (unsigned)f2bf(kx * cs - ky * sn) |
                  ((unsigned)f2bf(kx * sn + ky * cs) << 16);
    *(unsigned*)(base + 2 * i) = pq;
    *(unsigned*)(base + 768 + 2 * i) = pk;
}

// ---------------------------------------------------------------------------
// In-place softmax on bf16 scores (scale already applied by GEMM epilogue).
__global__ __launch_bounds__(256) void softmax_kernel(
    u16* __restrict__ P, int causal)
{
    __shared__ float sred[4];
    int row = blockIdx.x;
    int s = row & (S_ - 1);
    u16* p = P + (long)row * S_;
    int tid = threadIdx.x;
    int lane = tid & 63, wid = tid >> 6;

    u16x4 raw = *(const u16x4*)(p + tid * 4);
    float v[4];
    float mx = -INFINITY;
    #pragma unroll
    for (int j = 0; j < 4; ++j) {
        int col = tid * 4 + j;
        float val = bf2f(raw[j]);
        if (causal && col > s) val = -INFINITY;
        v[j] = val;
        mx = fmaxf(mx, val);
    }
    #pragma unroll
    for (int off = 1; off < 64; off <<= 1)
        mx = fmaxf(mx, __shfl_xor(mx, off, 64));
    if (lane == 0) sred[wid] = mx;
    __syncthreads();
    mx = fmaxf(fmaxf(sred[0], sred[1]), fmaxf(sred[2], sred[3]));
    __syncthreads();

    float sum = 0.f;
    #pragma unroll
    for (int j = 0; j < 4; ++j) {
        v[j] = __expf(v[j] - mx);
        sum += v[j];
    }
    #pragma unroll
    for (int off = 1; off < 64; off <<= 1)
        sum += __shfl_xor(sum, off, 64);
    if (lane == 0) sred[wid] = sum;
    __syncthreads();
    sum = sred[0] + sred[1] + sred[2] + sred[3];

    float invs = 1.f / sum;
    u16x4 o;
    #pragma unroll
    for (int j = 0; j < 4; ++j) o[j] = f2bf(v[j] * invs);
    *(u16x4*)(p + tid * 4) = o;
}

// ---------------------------------------------------------------------------
// x = LN(x + h)*g + b (fp32 state); bf16 mirror written to xb. float4 path.
__global__ __launch_bounds__(256) void add_ln_kernel(
    float* __restrict__ x, const float* __restrict__ h,
    const float* __restrict__ gb, u16* __restrict__ xb)
{
    __shared__ float sred[4];
    int row = blockIdx.x;
    int tid = threadIdx.x;
    int lane = tid & 63, wid = tid >> 6;
    float4* xr = (float4*)(x + (long)row * E_);
    const float4* hr = (const float4*)(h + (long)row * E_);

    float4 v = make_float4(0.f, 0.f, 0.f, 0.f);
    float sum = 0.f, sq = 0.f;
    if (tid < 192) {
        float4 a = xr[tid];
        float4 b = hr[tid];
        v.x = a.x + b.x; v.y = a.y + b.y; v.z = a.z + b.z; v.w = a.w + b.w;
        sum = v.x + v.y + v.z + v.w;
        sq  = v.x*v.x + v.y*v.y + v.z*v.z + v.w*v.w;
    }

    #pragma unroll
    for (int off = 1; off < 64; off <<= 1) sum += __shfl_xor(sum, off, 64);
    if (lane == 0) sred[wid] = sum;
    __syncthreads();
    sum = sred[0] + sred[1] + sred[2] + sred[3];
    __syncthreads();

    #pragma unroll
    for (int off = 1; off < 64; off <<= 1) sq += __shfl_xor(sq, off, 64);
    if (lane == 0) sred[wid] = sq;
    __syncthreads();
    sq = sred[0] + sred[1] + sred[2] + sred[3];

    float mu  = sum * (1.f / E_);
    float var = sq * (1.f / E_) - mu * mu;
    float inv = rsqrtf(var + 1e-5f);

    if (tid < 192) {
        const float4* g4 = (const float4*)gb;
        const float4* b4 = (const float4*)(gb + E_);
        float4 g = g4[tid], bb = b4[tid];
        float4 o;
        o.x = (v.x - mu) * inv * g.x + bb.x;
        o.y = (v.y - mu) * inv * g.y + bb.y;
        o.z = (v.z - mu) * inv * g.z + bb.z;
        o.w = (v.w - mu) * inv * g.w + bb.w;
        xr[tid] = o;
        u16x4 ob = { f2bf(o.x), f2bf(o.y), f2bf(o.z), f2bf(o.w) };
        *(u16x4*)(xb + (long)row * E_ + tid * 4) = ob;
    }
}

// ---------------------------------------------------------------------------
extern "C" void kernel_launch(void* const* d_in, const int* in_sizes, int n_in,
                              void* d_out, int out_size, void* d_ws, size_t ws_size,
                              hipStream_t stream) {
    const int*   seq       = (const int*)d_in[0];
    const float* embed     = (const float*)d_in[2];
    const float* enc_qkv_w = (const float*)d_in[3];
    const float* enc_qkv_b = (const float*)d_in[4];
    const float* enc_ln    = (const float*)d_in[5];
    const float* enc_w1    = (const float*)d_in[6];
    const float* enc_b1    = (const float*)d_in[7];
    const float* enc_w2    = (const float*)d_in[8];
    const float* enc_b2    = (const float*)d_in[9];
    const float* dec_qkv_w = (const float*)d_in[10];
    const float* dec_qkv_b = (const float*)d_in[11];
    const float* dec_ln    = (const float*)d_in[12];
    const float* dec_w1    = (const float*)d_in[13];
    const float* dec_b1    = (const float*)d_in[14];
    const float* dec_w2    = (const float*)d_in[15];
    const float* dec_b2    = (const float*)d_in[16];
    const float* unembed   = (const float*)d_in[17];

    const long TE  = (long)T_TOK * E_;
    const long TH  = (long)T_TOK * H_;
    const long SE  = (long)S_ * E_;
    const long SS  = (long)S_ * S_;
    const long SS4 = (long)B_ * SS;
    const long EE  = (long)E_ * E_;
    const long EH  = (long)E_ * H_;
    const long VE  = (long)V_ * E_;
    const long TQ  = (long)T_TOK * 2304;
    const long SQ  = (long)S_ * 2304;
    const long TABF = (long)S_ * 384 * 2;     // floats

    float*  ws    = (float*)d_ws;
    float*  f_x   = ws;
    float*  f_emb = ws + TE;
    float*  f_h   = ws + 2 * TE;
    float2* f_tab = (float2*)(ws + 3 * TE);

    u16* u_xb  = (u16*)(ws + 3 * TE + TABF);
    u16* u_enc = u_xb + TE;             // 5*TE
    u16* u_qkv = u_enc + 5 * TE;        // TQ
    u16* u_vT  = u_qkv + TQ;            // TE
    u16* u_hid = u_vT + TE;             // TH
    u16* u_P   = u_hid + TH;            // SS4 (scores+probs, in place)
    u16* u_w   = u_P + SS4;

    const long WTOT = 45 * EE + 20 * EH + VE;
    size_t need_persist = (size_t)((char*)(u_w + WTOT) - (char*)d_ws);
    bool persist = ws_size >= need_persist;

    u16* pw_eqkv = u_w;
    u16* pw_dqkv = pw_eqkv + 15 * EE;
    u16* pw_ew1  = pw_dqkv + 30 * EE;
    u16* pw_ew2  = pw_ew1 + 5 * EH;
    u16* pw_dw1  = pw_ew2 + 5 * EH;
    u16* pw_dw2  = pw_dw1 + 5 * EH;
    u16* pw_un   = pw_dw2 + 5 * EH;

    const float SCALE = 0.03608439182435161f; // 1/sqrt(768)

    auto T = [&](const float* in, u16* out, int R, int C, int z) {
        dim3 g(C / 32, R / 32, z);
        tcvt<float><<<g, 256, 0, stream>>>(in, out, C, R, (long)R * C, (long)R * C);
    };
    auto WTz = [&](const float* w, int R, int C, int z, u16* pp) -> const u16* {
        if (persist) return pp;
        T(w, u_w, R, C, z);
        return u_w;
    };
    auto G = [&](const u16* A, const u16* Bm, void* C, int M, int N, int K,
                 const float* bias, int relu, int obf, float alpha,
                 int lda, int ldb, int ldc,
                 int batch, long sA, long sB, long sC) {
        dim3 g(N / 128, M / 128, batch);
        if (obf) {
            if (relu) mgemm<1,1,1><<<g,256,0,stream>>>(A,Bm,C,bias,alpha,M,N,K,lda,ldb,ldc,sA,sB,sC);
            else if (bias) mgemm<1,0,1><<<g,256,0,stream>>>(A,Bm,C,bias,alpha,M,N,K,lda,ldb,ldc,sA,sB,sC);
            else mgemm<1,0,0><<<g,256,0,stream>>>(A,Bm,C,bias,alpha,M,N,K,lda,ldb,ldc,sA,sB,sC);
        } else {
            if (relu) mgemm<0,1,1><<<g,256,0,stream>>>(A,Bm,C,bias,alpha,M,N,K,lda,ldb,ldc,sA,sB,sC);
            else if (bias) mgemm<0,0,1><<<g,256,0,stream>>>(A,Bm,C,bias,alpha,M,N,K,lda,ldb,ldc,sA,sB,sC);
            else mgemm<0,0,0><<<g,256,0,stream>>>(A,Bm,C,bias,alpha,M,N,K,lda,ldb,ldc,sA,sB,sC);
        }
    };
    auto G8 = [&](const u16* A, const u16* Bm, void* C, int M, int N, int K,
                  const float* bias, int relu, int obf,
                  int lda, int ldb, int ldc) {
        dim3 g(N / 256, M / 256, 1);
        if (obf) {
            if (relu) mgemm8<1,1,1><<<g,512,0,stream>>>(A,Bm,C,bias,1.f,M,N,K,lda,ldb,ldc);
            else if (bias) mgemm8<1,0,1><<<g,512,0,stream>>>(A,Bm,C,bias,1.f,M,N,K,lda,ldb,ldc);
            else mgemm8<1,0,0><<<g,512,0,stream>>>(A,Bm,C,bias,1.f,M,N,K,lda,ldb,ldc);
        } else {
            mgemm8<0,0,0><<<g,512,0,stream>>>(A,Bm,C,bias,1.f,M,N,K,lda,ldb,ldc);
        }
    };
    // attention tail: rope -> V^T -> QK^T(bf16,scaled) -> softmax -> PV
    auto attn_tail = [&](int causal) {
        rope_kernel<<<T_TOK, 384, 0, stream>>>(u_qkv, f_tab);
        { dim3 g(E_ / 32, S_ / 32, B_);
          tcvt<u16><<<g, 256, 0, stream>>>(u_qkv + 1536, u_vT, 2304, S_, SQ, SE); }
        G(u_qkv, u_qkv + 768, u_P, S_, S_, E_, nullptr, 0, 1, SCALE,
          2304, 2304, S_, B_, SQ, SQ, SS);
        softmax_kernel<<<T_TOK, 256, 0, stream>>>(u_P, causal);
        G(u_P, u_vT, f_h, S_, E_, S_, nullptr, 0, 0, 1.f,
          S_, S_, E_, B_, SS, SE, SE);
    };

    if (persist) {
        T(enc_qkv_w, pw_eqkv, E_, E_, 15);
        T(dec_qkv_w, pw_dqkv, E_, E_, 30);
        T(enc_w1, pw_ew1, E_, H_, L_);
        T(enc_w2, pw_ew2, H_, E_, L_);
        T(dec_w1, pw_dw1, E_, H_, L_);
        T(dec_w2, pw_dw2, H_, E_, L_);
        T(unembed, pw_un, E_, V_, 1);
    }

    rope_tab_kernel<<<S_, 384, 0, stream>>>(f_tab);
    gather_kernel<<<T_TOK, 256, 0, stream>>>(seq, embed, f_emb, f_x, u_xb);

    // ------------------------ encoder ------------------------
    for (int i = 0; i < L_; ++i) {
        const u16* xsrc = (i == 0) ? u_xb : u_enc + (long)(i - 1) * TE;
        const float* bb = enc_qkv_b + (long)i * 3 * E_;
        G8(xsrc, WTz(enc_qkv_w + (long)i * 3 * EE, E_, E_, 3, pw_eqkv + (long)i * 3 * EE),
           u_qkv, T_TOK, 2304, E_, bb, 0, 1, E_, E_, 2304);
        attn_tail(0);
        add_ln_kernel<<<T_TOK, 256, 0, stream>>>(f_x, f_h, enc_ln + (2L * i + 0) * 2 * E_, u_xb);
        G8(u_xb, WTz(enc_w1 + (long)i * EH, E_, H_, 1, pw_ew1 + (long)i * EH),
           u_hid, T_TOK, H_, E_, enc_b1 + (long)i * H_, 1, 1, E_, E_, H_);
        G(u_hid, WTz(enc_w2 + (long)i * EH, H_, E_, 1, pw_ew2 + (long)i * EH),
          f_h, T_TOK, E_, H_, enc_b2 + (long)i * E_, 1, 0, 1.f, H_, H_, E_, 1, 0, 0, 0);
        add_ln_kernel<<<T_TOK, 256, 0, stream>>>(f_x, f_h, enc_ln + (2L * i + 1) * 2 * E_,
                                                 u_enc + (long)i * TE);
    }

    // ------------------------ decoder ------------------------
    seed_kernel<<<1024, 256, 0, stream>>>((const float4*)f_emb, (float4*)f_x, u_xb, TE / 4);
    for (int i = 0; i < L_; ++i) {
        const u16* kv_bf = u_enc + (long)i * TE;
        const float* bb = dec_qkv_b + (long)i * 6 * E_;

        // self-attention (causal), fused QKV
        G8(u_xb, WTz(dec_qkv_w + (long)i * 6 * EE, E_, E_, 3, pw_dqkv + (long)i * 6 * EE),
           u_qkv, T_TOK, 2304, E_, bb, 0, 1, E_, E_, 2304);
        attn_tail(1);
        add_ln_kernel<<<T_TOK, 256, 0, stream>>>(f_x, f_h, dec_ln + (3L * i + 0) * 2 * E_, u_xb);

        // cross-attention: Q from x, fused K/V from enc_out
        G(u_xb, WTz(dec_qkv_w + ((long)i * 6 + 3) * EE, E_, E_, 1, pw_dqkv + ((long)i * 6 + 3) * EE),
          u_qkv, T_TOK, E_, E_, bb + 3 * E_, 0, 1, 1.f, E_, E_, 2304, 1, 0, 0, 0);
        G(kv_bf, WTz(dec_qkv_w + ((long)i * 6 + 4) * EE, E_, E_, 2, pw_dqkv + ((long)i * 6 + 4) * EE),
          u_qkv + 768, T_TOK, 1536, E_, bb + 4 * E_, 0, 1, 1.f, E_, E_, 2304, 1, 0, 0, 0);
        attn_tail(0);
        add_ln_kernel<<<T_TOK, 256, 0, stream>>>(f_x, f_h, dec_ln + (3L * i + 1) * 2 * E_, u_xb);

        // MLP
        G8(u_xb, WTz(dec_w1 + (long)i * EH, E_, H_, 1, pw_dw1 + (long)i * EH),
           u_hid, T_TOK, H_, E_, dec_b1 + (long)i * H_, 1, 1, E_, E_, H_);
        G(u_hid, WTz(dec_w2 + (long)i * EH, H_, E_, 1, pw_dw2 + (long)i * EH),
          f_h, T_TOK, E_, H_, dec_b2 + (long)i * E_, 1, 0, 1.f, H_, H_, E_, 1, 0, 0, 0);
        add_ln_kernel<<<T_TOK, 256, 0, stream>>>(f_x, f_h, dec_ln + (3L * i + 2) * 2 * E_, u_xb);
    }

    // ------------------------ unembed ------------------------
    G8(u_xb, WTz(unembed, E_, V_, 1, pw_un), d_out, T_TOK, V_, E_,
       nullptr, 0, 0, E_, E_, V_);
}

// Round 5
// 2616.088 us; speedup vs baseline: 1.0458x; 1.0458x over previous
//
#include <hip/hip_runtime.h>
#include <math.h>
#include <stdint.h>

#define B_ 4
#define S_ 1024
#define E_ 768
#define H_ 3072
#define V_ 16384
#define L_ 5
#define T_TOK 4096   // B_*S_

typedef unsigned short u16;
typedef short bf16x8 __attribute__((ext_vector_type(8)));
typedef float floatx4 __attribute__((ext_vector_type(4)));
typedef u16 u16x4 __attribute__((ext_vector_type(4)));

__device__ __forceinline__ u16 f2bf(float f) {
    union { float f; unsigned u; } x; x.f = f;
    unsigned r = (x.u + 0x7FFFu + ((x.u >> 16) & 1u)) >> 16;
    return (u16)r;
}
__device__ __forceinline__ float bf2f(u16 v) {
    union { unsigned u; float f; } x; x.u = ((unsigned)v) << 16;
    return x.f;
}

__device__ __forceinline__ void gload16(const void* g, void* l) {
    __builtin_amdgcn_global_load_lds(
        (const __attribute__((address_space(1))) unsigned int*)(uintptr_t)g,
        (__attribute__((address_space(3))) unsigned int*)(uintptr_t)l,
        16, 0, 0);
}

__device__ __forceinline__ void bar_sync() {
    asm volatile("s_waitcnt vmcnt(0)" ::: "memory");
    __builtin_amdgcn_s_barrier();
    asm volatile("" ::: "memory");
}

// rope rotate helper: v at column col (pair = lane^1), i = (col>>1)%384
__device__ __forceinline__ float rope_rot(float v, long row, long col, int lane,
                                          const float2* __restrict__ tab) {
    float vp = __shfl_xor(v, 1, 64);
    int s = (int)(row & (S_ - 1));
    int ii = ((int)col >> 1) % 384;
    float2 f = tab[(long)s * 384 + ii];
    return (lane & 1) ? (vp * f.y + v * f.x) : (v * f.x - vp * f.y);
}

// ---------------------------------------------------------------------------
// 128x128 2-phase kernel. BIAS: 0 none, 1 per-col, 2 per-row.
#define BK 32

template<int OBF, int RELU, int BIAS, int ROPE>
__global__ __launch_bounds__(256) void mgemm(
    const u16* __restrict__ A, const u16* __restrict__ B, void* __restrict__ Cv,
    const float* __restrict__ bias, const float2* __restrict__ tab,
    float alpha, int M, int N, int K,
    int lda, int ldb, int ldc,
    long sA, long sB, long sC)
{
    __shared__ u16 As[2][128 * BK];
    __shared__ u16 Bs[2][128 * BK];

    const int tid  = threadIdx.x;
    const int lane = tid & 63;
    const int wid  = tid >> 6;
    const int wr   = (wid >> 1) * 64;
    const int wc   = (wid & 1) * 64;
    const int lr   = lane & 15;
    const int kg   = lane >> 4;

    const long rowBase = (long)blockIdx.y * 128;
    const long colBase = (long)blockIdx.x * 128;

    const u16* Ab = A + (long)blockIdx.z * sA;
    const u16* Bb = B + (long)blockIdx.z * sB;

    const int c0 = tid, c1 = tid + 256;
    const int ar0 = c0 >> 2, ac0 = (c0 & 3) ^ ((ar0 >> 1) & 3);
    const int ar1 = c1 >> 2, ac1 = (c1 & 3) ^ ((ar1 >> 1) & 3);

    const u16* pa0 = Ab + (rowBase + ar0) * (long)lda + ac0 * 8;
    const u16* pa1 = Ab + (rowBase + ar1) * (long)lda + ac1 * 8;
    const u16* pb0 = Bb + (colBase + ar0) * (long)ldb + ac0 * 8;
    const u16* pb1 = Bb + (colBase + ar1) * (long)ldb + ac1 * 8;

    int aoff[4], boff[4];
    #pragma unroll
    for (int m = 0; m < 4; ++m) {
        int r = wr + m * 16 + lr;
        aoff[m] = r * 32 + ((kg ^ ((r >> 1) & 3)) << 3);
        int c = wc + m * 16 + lr;
        boff[m] = c * 32 + ((kg ^ ((c >> 1) & 3)) << 3);
    }

    floatx4 acc[4][4];
    #pragma unroll
    for (int m = 0; m < 4; ++m)
        #pragma unroll
        for (int n = 0; n < 4; ++n)
            acc[m][n] = (floatx4)0.f;

    auto stage = [&](int buf, int k0) {
        gload16(pa0 + k0, &As[buf][c0 * 8]);
        gload16(pa1 + k0, &As[buf][c1 * 8]);
        gload16(pb0 + k0, &Bs[buf][c0 * 8]);
        gload16(pb1 + k0, &Bs[buf][c1 * 8]);
    };

    const int NT = K / BK;
    stage(0, 0);
    bar_sync();

    for (int t = 0; t < NT; ++t) {
        const int cur = t & 1;
        if (t + 1 < NT) stage(cur ^ 1, (t + 1) * BK);

        bf16x8 af[4], bfr[4];
        #pragma unroll
        for (int m = 0; m < 4; ++m) af[m]  = *(const bf16x8*)(&As[cur][aoff[m]]);
        #pragma unroll
        for (int n = 0; n < 4; ++n) bfr[n] = *(const bf16x8*)(&Bs[cur][boff[n]]);
        #pragma unroll
        for (int m = 0; m < 4; ++m)
            #pragma unroll
            for (int n = 0; n < 4; ++n)
                acc[m][n] = __builtin_amdgcn_mfma_f32_16x16x32_bf16(
                                af[m], bfr[n], acc[m][n], 0, 0, 0);

        if (t + 1 < NT) bar_sync();
    }

    const long col0 = colBase + wc + lr;
    const long row0 = rowBase + wr + kg * 4;
    #pragma unroll
    for (int n = 0; n < 4; ++n) {
        long col = col0 + n * 16;
        float bvc = (BIAS == 1) ? bias[col] : 0.f;
        #pragma unroll
        for (int m = 0; m < 4; ++m)
            #pragma unroll
            for (int j = 0; j < 4; ++j) {
                long row = row0 + m * 16 + j;
                float v = acc[m][n][j] * alpha + bvc;
                if (BIAS == 2) v += bias[row];
                if (ROPE) v = rope_rot(v, row, col, lane, tab);
                if (RELU) v = fmaxf(v, 0.f);
                if (OBF) ((u16*)Cv + (long)blockIdx.z * sC)[row * (long)ldc + col] = f2bf(v);
                else     ((float*)Cv + (long)blockIdx.z * sC)[row * (long)ldc + col] = v;
            }
    }
}

// ---------------------------------------------------------------------------
// 64x128 2-phase kernel (for N=768-class GEMMs: 2x grid of the 128^2 tile).
template<int OBF, int RELU, int BIAS, int ROPE>
__global__ __launch_bounds__(256) void mgemm64(
    const u16* __restrict__ A, const u16* __restrict__ B, void* __restrict__ Cv,
    const float* __restrict__ bias, const float2* __restrict__ tab,
    float alpha, int M, int N, int K,
    int lda, int ldb, int ldc,
    long sA, long sB, long sC)
{
    __shared__ u16 As[2][64 * BK];
    __shared__ u16 Bs[2][128 * BK];

    const int tid  = threadIdx.x;
    const int lane = tid & 63;
    const int wid  = tid >> 6;          // 0..3, wave owns 64M x 32N
    const int lr   = lane & 15;
    const int kg   = lane >> 4;

    const long rowBase = (long)blockIdx.y * 64;
    const long colBase = (long)blockIdx.x * 128;

    const u16* Ab = A + (long)blockIdx.z * sA;
    const u16* Bb = B + (long)blockIdx.z * sB;

    // A: 256 chunks (1/thread); B: 512 chunks (2/thread)
    const int ra = tid >> 2, cha = (tid & 3) ^ ((ra >> 1) & 3);
    const int c0 = tid, c1 = tid + 256;
    const int rb0 = c0 >> 2, chb0 = (c0 & 3) ^ ((rb0 >> 1) & 3);
    const int rb1 = c1 >> 2, chb1 = (c1 & 3) ^ ((rb1 >> 1) & 3);

    const u16* pa  = Ab + (rowBase + ra)  * (long)lda + cha  * 8;
    const u16* pb0 = Bb + (colBase + rb0) * (long)ldb + chb0 * 8;
    const u16* pb1 = Bb + (colBase + rb1) * (long)ldb + chb1 * 8;

    int aoff[4], boff[2];
    #pragma unroll
    for (int m = 0; m < 4; ++m) {
        int r = m * 16 + lr;
        aoff[m] = r * 32 + ((kg ^ ((r >> 1) & 3)) << 3);
    }
    #pragma unroll
    for (int n = 0; n < 2; ++n) {
        int c = wid * 32 + n * 16 + lr;
        boff[n] = c * 32 + ((kg ^ ((c >> 1) & 3)) << 3);
    }

    floatx4 acc[4][2];
    #pragma unroll
    for (int m = 0; m < 4; ++m)
        #pragma unroll
        for (int n = 0; n < 2; ++n)
            acc[m][n] = (floatx4)0.f;

    auto stage = [&](int buf, int k0) {
        gload16(pa  + k0, &As[buf][tid * 8]);
        gload16(pb0 + k0, &Bs[buf][c0 * 8]);
        gload16(pb1 + k0, &Bs[buf][c1 * 8]);
    };

    const int NT = K / BK;
    stage(0, 0);
    bar_sync();

    for (int t = 0; t < NT; ++t) {
        const int cur = t & 1;
        if (t + 1 < NT) stage(cur ^ 1, (t + 1) * BK);

        bf16x8 af[4], bfr[2];
        #pragma unroll
        for (int m = 0; m < 4; ++m) af[m]  = *(const bf16x8*)(&As[cur][aoff[m]]);
        #pragma unroll
        for (int n = 0; n < 2; ++n) bfr[n] = *(const bf16x8*)(&Bs[cur][boff[n]]);
        #pragma unroll
        for (int m = 0; m < 4; ++m)
            #pragma unroll
            for (int n = 0; n < 2; ++n)
                acc[m][n] = __builtin_amdgcn_mfma_f32_16x16x32_bf16(
                                af[m], bfr[n], acc[m][n], 0, 0, 0);

        if (t + 1 < NT) bar_sync();
    }

    const long col0 = colBase + wid * 32 + lr;
    const long row0 = rowBase + kg * 4;
    #pragma unroll
    for (int n = 0; n < 2; ++n) {
        long col = col0 + n * 16;
        float bvc = (BIAS == 1) ? bias[col] : 0.f;
        #pragma unroll
        for (int m = 0; m < 4; ++m)
            #pragma unroll
            for (int j = 0; j < 4; ++j) {
                long row = row0 + m * 16 + j;
                float v = acc[m][n][j] * alpha + bvc;
                if (BIAS == 2) v += bias[row];
                if (ROPE) v = rope_rot(v, row, col, lane, tab);
                if (RELU) v = fmaxf(v, 0.f);
                if (OBF) ((u16*)Cv + (long)blockIdx.z * sC)[row * (long)ldc + col] = f2bf(v);
                else     ((float*)Cv + (long)blockIdx.z * sC)[row * (long)ldc + col] = v;
            }
    }
}

// ---------------------------------------------------------------------------
// 256x256 8-wave phase-split pipelined GEMM — unembed only (1024 blocks).
template<int OBF, int RELU, int BIAS>
__global__ __launch_bounds__(512, 2) void mgemm8(
    const u16* __restrict__ A, const u16* __restrict__ B, void* __restrict__ Cv,
    const float* __restrict__ bias, float alpha, int M, int N, int K,
    int lda, int ldb, int ldc)
{
    __shared__ u16 As[3][256 * 32];
    __shared__ u16 Bs[3][256 * 32];

    const int tid  = threadIdx.x;
    const int lane = tid & 63;
    const int wid  = tid >> 6;
    const int wm   = wid >> 2;
    const int wn   = wid & 3;
    const int lr   = lane & 15;
    const int kg   = lane >> 4;

    const long rowBase = (long)blockIdx.y * 256;
    const long colBase = (long)blockIdx.x * 256;

    const int c0 = tid, c1 = tid + 512;
    const int r0 = c0 >> 2, ch0 = (c0 & 3) ^ ((r0 >> 1) & 3);
    const int r1 = c1 >> 2, ch1 = (c1 & 3) ^ ((r1 >> 1) & 3);

    const u16* pa0 = A + (rowBase + r0) * (long)lda + ch0 * 8;
    const u16* pa1 = A + (rowBase + r1) * (long)lda + ch1 * 8;
    const u16* pb0 = B + (colBase + r0) * (long)ldb + ch0 * 8;
    const u16* pb1 = B + (colBase + r1) * (long)ldb + ch1 * 8;

    int aoff[8], boff[4];
    #pragma unroll
    for (int mi = 0; mi < 8; ++mi) {
        int r = wm * 128 + mi * 16 + lr;
        aoff[mi] = r * 32 + ((kg ^ ((r >> 1) & 3)) << 3);
    }
    #pragma unroll
    for (int ni = 0; ni < 4; ++ni) {
        int c = wn * 64 + ni * 16 + lr;
        boff[ni] = c * 32 + ((kg ^ ((c >> 1) & 3)) << 3);
    }

    floatx4 acc[8][4];
    #pragma unroll
    for (int mi = 0; mi < 8; ++mi)
        #pragma unroll
        for (int ni = 0; ni < 4; ++ni)
            acc[mi][ni] = (floatx4)0.f;

    auto stageA = [&](int buf, int kt) {
        gload16(pa0 + (long)kt * 32, &As[buf][c0 * 8]);
        gload16(pa1 + (long)kt * 32, &As[buf][c1 * 8]);
    };
    auto stageB = [&](int buf, int kt) {
        gload16(pb0 + (long)kt * 32, &Bs[buf][c0 * 8]);
        gload16(pb1 + (long)kt * 32, &Bs[buf][c1 * 8]);
    };

    const int NT = K / 32;
    stageA(0, 0); stageB(0, 0);
    stageA(1, 1); stageB(1, 1);
    asm volatile("s_waitcnt vmcnt(4)" ::: "memory");
    __builtin_amdgcn_sched_barrier(0);
    __builtin_amdgcn_s_barrier();

    int b0 = 0, b1 = 1, b2 = 2;
    for (int t = 0; t < NT; ++t) {
        bf16x8 afr[4], bfr[4];
        if (t + 2 < NT) stageA(b2, t + 2);
        #pragma unroll
        for (int mi = 0; mi < 4; ++mi) afr[mi] = *(const bf16x8*)(&As[b0][aoff[mi]]);
        #pragma unroll
        for (int ni = 0; ni < 4; ++ni) bfr[ni] = *(const bf16x8*)(&Bs[b0][boff[ni]]);
        __builtin_amdgcn_s_barrier();
        asm volatile("s_waitcnt lgkmcnt(0)" ::: "memory");
        __builtin_amdgcn_sched_barrier(0);
        __builtin_amdgcn_s_setprio(1);
        #pragma unroll
        for (int mi = 0; mi < 4; ++mi)
            #pragma unroll
            for (int ni = 0; ni < 4; ++ni)
                acc[mi][ni] = __builtin_amdgcn_mfma_f32_16x16x32_bf16(
                                  afr[mi], bfr[ni], acc[mi][ni], 0, 0, 0);
        __builtin_amdgcn_s_setprio(0);
        __builtin_amdgcn_sched_barrier(0);
        __builtin_amdgcn_s_barrier();
        if (t + 2 < NT) stageB(b2, t + 2);
        #pragma unroll
        for (int mi = 0; mi < 4; ++mi) afr[mi] = *(const bf16x8*)(&As[b0][aoff[4 + mi]]);
        __builtin_amdgcn_s_barrier();
        asm volatile("s_waitcnt lgkmcnt(0)" ::: "memory");
        __builtin_amdgcn_sched_barrier(0);
        __builtin_amdgcn_s_setprio(1);
        #pragma unroll
        for (int mi = 0; mi < 4; ++mi)
            #pragma unroll
            for (int ni = 0; ni < 4; ++ni)
                acc[4 + mi][ni] = __builtin_amdgcn_mfma_f32_16x16x32_bf16(
                                      afr[mi], bfr[ni], acc[4 + mi][ni], 0, 0, 0);
        __builtin_amdgcn_s_setprio(0);
        __builtin_amdgcn_sched_barrier(0);
        if (t + 2 < NT) { asm volatile("s_waitcnt vmcnt(4)" ::: "memory"); }
        else            { asm volatile("s_waitcnt vmcnt(0)" ::: "memory"); }
        __builtin_amdgcn_sched_barrier(0);
        __builtin_amdgcn_s_barrier();
        int tb = b0; b0 = b1; b1 = b2; b2 = tb;
    }

    const long col0 = colBase + wn * 64 + lr;
    const long row0 = rowBase + wm * 128 + kg * 4;
    #pragma unroll
    for (int ni = 0; ni < 4; ++ni) {
        long col = col0 + ni * 16;
        float bv = BIAS ? bias[col] : 0.f;
        #pragma unroll
        for (int mi = 0; mi < 8; ++mi)
            #pragma unroll
            for (int j = 0; j < 4; ++j) {
                float v = acc[mi][ni][j] * alpha + bv;
                if (RELU) v = fmaxf(v, 0.f);
                if (OBF) ((u16*)Cv)[(row0 + mi * 16 + j) * (long)ldc + col] = f2bf(v);
                else     ((float*)Cv)[(row0 + mi * 16 + j) * (long)ldc + col] = v;
            }
    }
}

// ---------------------------------------------------------------------------
// fp32 [R][C] -> bf16 [C][R] weight transpose-convert.
__global__ __launch_bounds__(256) void tcvt(
    const float* __restrict__ in, u16* __restrict__ out,
    int ldIn, int ldOut, long sIn, long sOut)
{
    __shared__ u16 t[32][33];
    const int tx = threadIdx.x & 31, ty = threadIdx.x >> 5;
    const long r0 = (long)blockIdx.y * 32, c0 = (long)blockIdx.x * 32;
    const float* ib = in + (long)blockIdx.z * sIn;
    u16* ob = out + (long)blockIdx.z * sOut;
    #pragma unroll
    for (int j = 0; j < 4; ++j) {
        int r = ty + j * 8;
        t[r][tx] = f2bf(ib[(r0 + r) * (long)ldIn + c0 + tx]);
    }
    __syncthreads();
    #pragma unroll
    for (int j = 0; j < 4; ++j) {
        int c = ty + j * 8;
        ob[(c0 + c) * (long)ldOut + r0 + tx] = t[tx][c];
    }
}

// ---------------------------------------------------------------------------
__global__ __launch_bounds__(256) void gather_kernel(
    const int* __restrict__ seq, const float* __restrict__ embed,
    float* __restrict__ f_emb, float* __restrict__ f_x, u16* __restrict__ xb)
{
    int t = blockIdx.x;
    int tok = seq[t];
    const float* src = embed + (long)tok * E_;
    long base = (long)t * E_;
    #pragma unroll
    for (int j = 0; j < 3; ++j) {
        int i = threadIdx.x + j * 256;
        float v = src[i];
        f_emb[base + i] = v;
        f_x[base + i] = v;
        xb[base + i] = f2bf(v);
    }
}

__global__ __launch_bounds__(256) void seed_kernel(
    const float4* __restrict__ src, float4* __restrict__ x,
    u16* __restrict__ xb, long n4)
{
    long i = (long)blockIdx.x * blockDim.x + threadIdx.x;
    long stride = (long)gridDim.x * blockDim.x;
    for (; i < n4; i += stride) {
        float4 v = src[i];
        x[i] = v;
        u16x4 b = { f2bf(v.x), f2bf(v.y), f2bf(v.z), f2bf(v.w) };
        *(u16x4*)(xb + i * 4) = b;
    }
}

// ---------------------------------------------------------------------------
__global__ __launch_bounds__(384) void rope_tab_kernel(float2* __restrict__ tab)
{
    int s = blockIdx.x;
    int i = threadIdx.x;
    float inv = expf(-(float)(2 * i) * (9.210340371976184f / (float)E_));
    float ang = (float)s * inv;
    float sn, cs;
    sincosf(ang, &sn, &cs);
    tab[(long)s * 384 + i] = make_float2(cs, sn);
}

// ---------------------------------------------------------------------------
// In-place softmax on bf16 scores (scale pre-applied). One block per row.
__global__ __launch_bounds__(256) void softmax_kernel(
    u16* __restrict__ P, int causal)
{
    __shared__ float sred[4];
    int row = blockIdx.x;
    int s = row & (S_ - 1);
    u16* p = P + (long)row * S_;
    int tid = threadIdx.x;
    int lane = tid & 63, wid = tid >> 6;

    u16x4 raw = *(const u16x4*)(p + tid * 4);
    float v[4];
    float mx = -INFINITY;
    #pragma unroll
    for (int j = 0; j < 4; ++j) {
        int col = tid * 4 + j;
        float val = bf2f(raw[j]);
        if (causal && col > s) val = -INFINITY;
        v[j] = val;
        mx = fmaxf(mx, val);
    }
    #pragma unroll
    for (int off = 1; off < 64; off <<= 1)
        mx = fmaxf(mx, __shfl_xor(mx, off, 64));
    if (lane == 0) sred[wid] = mx;
    __syncthreads();
    mx = fmaxf(fmaxf(sred[0], sred[1]), fmaxf(sred[2], sred[3]));
    __syncthreads();

    float sum = 0.f;
    #pragma unroll
    for (int j = 0; j < 4; ++j) {
        v[j] = __expf(v[j] - mx);
        sum += v[j];
    }
    #pragma unroll
    for (int off = 1; off < 64; off <<= 1)
        sum += __shfl_xor(sum, off, 64);
    if (lane == 0) sred[wid] = sum;
    __syncthreads();
    sum = sred[0] + sred[1] + sred[2] + sred[3];

    float invs = 1.f / sum;
    u16x4 o;
    #pragma unroll
    for (int j = 0; j < 4; ++j) o[j] = f2bf(v[j] * invs);
    *(u16x4*)(p + tid * 4) = o;
}

// ---------------------------------------------------------------------------
// x = LN(x + h)*g + b; bf16 mirror to xb. One WAVE per row, 4 rows/block.
__global__ __launch_bounds__(256) void add_ln_kernel(
    float* __restrict__ x, const float* __restrict__ h,
    const float* __restrict__ gb, u16* __restrict__ xb)
{
    int row = blockIdx.x * 4 + (threadIdx.x >> 6);
    int lane = threadIdx.x & 63;
    float4* xr = (float4*)(x + (long)row * E_);
    const float4* hr = (const float4*)(h + (long)row * E_);

    float4 v[3];
    float sum = 0.f, sq = 0.f;
    #pragma unroll
    for (int l = 0; l < 3; ++l) {
        int idx = l * 64 + lane;
        float4 a = xr[idx];
        float4 b = hr[idx];
        v[l].x = a.x + b.x; v[l].y = a.y + b.y;
        v[l].z = a.z + b.z; v[l].w = a.w + b.w;
        sum += v[l].x + v[l].y + v[l].z + v[l].w;
        sq  += v[l].x*v[l].x + v[l].y*v[l].y + v[l].z*v[l].z + v[l].w*v[l].w;
    }
    #pragma unroll
    for (int off = 1; off < 64; off <<= 1) {
        sum += __shfl_xor(sum, off, 64);
        sq  += __shfl_xor(sq,  off, 64);
    }

    float mu  = sum * (1.f / E_);
    float var = sq * (1.f / E_) - mu * mu;
    float inv = rsqrtf(var + 1e-5f);

    const float4* g4 = (const float4*)gb;
    const float4* b4 = (const float4*)(gb + E_);
    #pragma unroll
    for (int l = 0; l < 3; ++l) {
        int idx = l * 64 + lane;
        float4 g = g4[idx], bb = b4[idx];
        float4 o;
        o.x = (v[l].x - mu) * inv * g.x + bb.x;
        o.y = (v[l].y - mu) * inv * g.y + bb.y;
        o.z = (v[l].z - mu) * inv * g.z + bb.z;
        o.w = (v[l].w - mu) * inv * g.w + bb.w;
        xr[idx] = o;
        u16x4 ob = { f2bf(o.x), f2bf(o.y), f2bf(o.z), f2bf(o.w) };
        *(u16x4*)(xb + (long)row * E_ + idx * 4) = ob;
    }
}

// ---------------------------------------------------------------------------
extern "C" void kernel_launch(void* const* d_in, const int* in_sizes, int n_in,
                              void* d_out, int out_size, void* d_ws, size_t ws_size,
                              hipStream_t stream) {
    const int*   seq       = (const int*)d_in[0];
    const float* embed     = (const float*)d_in[2];
    const float* enc_qkv_w = (const float*)d_in[3];
    const float* enc_qkv_b = (const float*)d_in[4];
    const float* enc_ln    = (const float*)d_in[5];
    const float* enc_w1    = (const float*)d_in[6];
    const float* enc_b1    = (const float*)d_in[7];
    const float* enc_w2    = (const float*)d_in[8];
    const float* enc_b2    = (const float*)d_in[9];
    const float* dec_qkv_w = (const float*)d_in[10];
    const float* dec_qkv_b = (const float*)d_in[11];
    const float* dec_ln    = (const float*)d_in[12];
    const float* dec_w1    = (const float*)d_in[13];
    const float* dec_b1    = (const float*)d_in[14];
    const float* dec_w2    = (const float*)d_in[15];
    const float* dec_b2    = (const float*)d_in[16];
    const float* unembed   = (const float*)d_in[17];

    const long TE  = (long)T_TOK * E_;
    const long TH  = (long)T_TOK * H_;
    const long SE  = (long)S_ * E_;
    const long SS  = (long)S_ * S_;
    const long SS4 = (long)B_ * SS;
    const long EE  = (long)E_ * E_;
    const long EH  = (long)E_ * H_;
    const long VE  = (long)V_ * E_;
    const long TQK = (long)T_TOK * 1536;
    const long SQK = (long)S_ * 1536;
    const long TABF = (long)S_ * 384 * 2;

    float*  ws    = (float*)d_ws;
    float*  f_x   = ws;
    float*  f_emb = ws + TE;
    float*  f_h   = ws + 2 * TE;
    float2* f_tab = (float2*)(ws + 3 * TE);

    u16* u_xb  = (u16*)(ws + 3 * TE + TABF);
    u16* u_enc = u_xb + TE;             // 5*TE
    u16* u_qk  = u_enc + 5 * TE;        // TQK = 2*TE
    u16* u_vT  = u_qk + TQK;            // TE  ([768][4096])
    u16* u_hid = u_vT + TE;             // TH
    u16* u_P   = u_hid + TH;            // SS4
    u16* u_w   = u_P + SS4;

    const long WTOT = 45 * EE + 20 * EH + VE;
    size_t need_persist = (size_t)((char*)(u_w + WTOT) - (char*)d_ws);
    bool persist = ws_size >= need_persist;

    u16* pw_eqkv = u_w;
    u16* pw_dqkv = pw_eqkv + 15 * EE;
    u16* pw_ew1  = pw_dqkv + 30 * EE;
    u16* pw_ew2  = pw_ew1 + 5 * EH;
    u16* pw_dw1  = pw_ew2 + 5 * EH;
    u16* pw_dw2  = pw_dw1 + 5 * EH;
    u16* pw_un   = pw_dw2 + 5 * EH;

    const float SCALE = 0.03608439182435161f; // 1/sqrt(768)

    auto T = [&](const float* in, u16* out, int R, int C, int z) {
        dim3 g(C / 32, R / 32, z);
        tcvt<<<g, 256, 0, stream>>>(in, out, C, R, (long)R * C, (long)R * C);
    };
    auto WTz = [&](const float* w, int R, int C, int z, u16* pp) -> const u16* {
        if (persist) return pp;
        T(w, u_w, R, C, z);
        return u_w;
    };

    if (persist) {
        T(enc_qkv_w, pw_eqkv, E_, E_, 15);
        T(dec_qkv_w, pw_dqkv, E_, E_, 30);
        T(enc_w1, pw_ew1, E_, H_, L_);
        T(enc_w2, pw_ew2, H_, E_, L_);
        T(dec_w1, pw_dw1, E_, H_, L_);
        T(dec_w2, pw_dw2, H_, E_, L_);
        T(unembed, pw_un, E_, V_, 1);
    }

    rope_tab_kernel<<<S_, 384, 0, stream>>>(f_tab);
    gather_kernel<<<T_TOK, 256, 0, stream>>>(seq, embed, f_emb, f_x, u_xb);

    // --- per-op launchers -------------------------------------------------
    // fused Q,K projection with rope (N=1536), bf16 out into u_qk
    auto qk_rope = [&](const u16* X, const u16* W, const float* bias) {
        dim3 g(1536 / 128, T_TOK / 128, 1);
        mgemm<1,0,1,1><<<g,256,0,stream>>>(X, W, u_qk, bias, f_tab, 1.f,
            T_TOK, 1536, E_, E_, E_, 1536, 0, 0, 0);
    };
    // single rope'd projection (cross Q to cols 0.., cross K to cols 768..)
    auto proj_rope64 = [&](const u16* X, const u16* W, u16* dst, const float* bias) {
        dim3 g(768 / 128, T_TOK / 64, 1);
        mgemm64<1,0,1,1><<<g,256,0,stream>>>(X, W, dst, bias, f_tab, 1.f,
            T_TOK, 768, E_, E_, E_, 1536, 0, 0, 0);
    };
    // V^T = Wv^T @ X^T  (M=768 d-rows, N=4096 tokens), row-bias
    auto vT_gemm = [&](const u16* Wv, const u16* X, const float* biasrow) {
        dim3 g(T_TOK / 128, 768 / 64, 1);
        mgemm64<1,0,2,0><<<g,256,0,stream>>>(Wv, X, u_vT, biasrow, nullptr, 1.f,
            768, T_TOK, E_, E_, E_, T_TOK, 0, 0, 0);
    };
    auto qkt = [&]() {
        dim3 g(S_ / 128, S_ / 128, B_);
        mgemm<1,0,0,0><<<g,256,0,stream>>>(u_qk, u_qk + 768, u_P, nullptr, nullptr,
            SCALE, S_, S_, E_, 1536, 1536, S_, SQK, SQK, SS);
    };
    auto pv = [&]() {
        dim3 g(E_ / 128, S_ / 64, B_);
        mgemm64<0,0,0,0><<<g,256,0,stream>>>(u_P, u_vT, f_h, nullptr, nullptr, 1.f,
            S_, E_, S_, S_, T_TOK, E_, SS, 1024, SE);
    };
    auto mlp1 = [&](const u16* W, const float* b1) {
        dim3 g(H_ / 128, T_TOK / 128, 1);
        mgemm<1,1,1,0><<<g,256,0,stream>>>(u_xb, W, u_hid, b1, nullptr, 1.f,
            T_TOK, H_, E_, E_, E_, H_, 0, 0, 0);
    };
    auto mlp2 = [&](const u16* W, const float* b2) {
        dim3 g(E_ / 128, T_TOK / 64, 1);
        mgemm64<0,1,1,0><<<g,256,0,stream>>>(u_hid, W, f_h, b2, nullptr, 1.f,
            T_TOK, E_, H_, H_, H_, E_, 0, 0, 0);
    };
    auto lnz = [&](const float* gb, u16* xbdst) {
        add_ln_kernel<<<T_TOK / 4, 256, 0, stream>>>(f_x, f_h, gb, xbdst);
    };
    auto sm = [&](int causal) {
        softmax_kernel<<<T_TOK, 256, 0, stream>>>(u_P, causal);
    };

    // ------------------------ encoder ------------------------
    for (int i = 0; i < L_; ++i) {
        const u16* xsrc = (i == 0) ? u_xb : u_enc + (long)(i - 1) * TE;
        const float* bb = enc_qkv_b + (long)i * 3 * E_;
        qk_rope(xsrc, WTz(enc_qkv_w + (long)i * 3 * EE, E_, E_, 2,
                          pw_eqkv + (long)i * 3 * EE), bb);
        vT_gemm(WTz(enc_qkv_w + ((long)i * 3 + 2) * EE, E_, E_, 1,
                    pw_eqkv + ((long)i * 3 + 2) * EE), xsrc, bb + 2 * E_);
        qkt();
        sm(0);
        pv();
        lnz(enc_ln + (2L * i + 0) * 2 * E_, u_xb);
        mlp1(WTz(enc_w1 + (long)i * EH, E_, H_, 1, pw_ew1 + (long)i * EH),
             enc_b1 + (long)i * H_);
        mlp2(WTz(enc_w2 + (long)i * EH, H_, E_, 1, pw_ew2 + (long)i * EH),
             enc_b2 + (long)i * E_);
        lnz(enc_ln + (2L * i + 1) * 2 * E_, u_enc + (long)i * TE);
    }

    // ------------------------ decoder ------------------------
    seed_kernel<<<1024, 256, 0, stream>>>((const float4*)f_emb, (float4*)f_x, u_xb, TE / 4);
    for (int i = 0; i < L_; ++i) {
        const u16* kv_bf = u_enc + (long)i * TE;
        const float* bb = dec_qkv_b + (long)i * 6 * E_;

        // self-attention (causal)
        qk_rope(u_xb, WTz(dec_qkv_w + (long)i * 6 * EE, E_, E_, 2,
                          pw_dqkv + (long)i * 6 * EE), bb);
        vT_gemm(WTz(dec_qkv_w + ((long)i * 6 + 2) * EE, E_, E_, 1,
                    pw_dqkv + ((long)i * 6 + 2) * EE), u_xb, bb + 2 * E_);
        qkt();
        sm(1);
        pv();
        lnz(dec_ln + (3L * i + 0) * 2 * E_, u_xb);

        // cross-attention
        proj_rope64(u_xb, WTz(dec_qkv_w + ((long)i * 6 + 3) * EE, E_, E_, 1,
                              pw_dqkv + ((long)i * 6 + 3) * EE), u_qk, bb + 3 * E_);
        proj_rope64(kv_bf, WTz(dec_qkv_w + ((long)i * 6 + 4) * EE, E_, E_, 1,
                               pw_dqkv + ((long)i * 6 + 4) * EE), u_qk + 768, bb + 4 * E_);
        vT_gemm(WTz(dec_qkv_w + ((long)i * 6 + 5) * EE, E_, E_, 1,
                    pw_dqkv + ((long)i * 6 + 5) * EE), kv_bf, bb + 5 * E_);
        qkt();
        sm(0);
        pv();
        lnz(dec_ln + (3L * i + 1) * 2 * E_, u_xb);

        // MLP
        mlp1(WTz(dec_w1 + (long)i * EH, E_, H_, 1, pw_dw1 + (long)i * EH),
             dec_b1 + (long)i * H_);
        mlp2(WTz(dec_w2 + (long)i * EH, H_, E_, 1, pw_dw2 + (long)i * EH),
             dec_b2 + (long)i * E_);
        lnz(dec_ln + (3L * i + 2) * 2 * E_, u_xb);
    }

    // ------------------------ unembed ------------------------
    {
        dim3 g(V_ / 256, T_TOK / 256, 1);
        mgemm8<0,0,0><<<g,512,0,stream>>>(u_xb, WTz(unembed, E_, V_, 1, pw_un),
            d_out, nullptr, 1.f, T_TOK, V_, E_, E_, E_, V_);
    }
}

// Round 6
// 2519.483 us; speedup vs baseline: 1.0859x; 1.0383x over previous
//
#include <hip/hip_runtime.h>
#include <math.h>
#include <stdint.h>

#define B_ 4
#define S_ 1024
#define E_ 768
#define H_ 3072
#define V_ 16384
#define L_ 5
#define T_TOK 4096   // B_*S_

typedef unsigned short u16;
typedef short bf16x8 __attribute__((ext_vector_type(8)));
typedef float floatx4 __attribute__((ext_vector_type(4)));
typedef u16 u16x4 __attribute__((ext_vector_type(4)));

__device__ __forceinline__ u16 f2bf(float f) {
    union { float f; unsigned u; } x; x.f = f;
    unsigned r = (x.u + 0x7FFFu + ((x.u >> 16) & 1u)) >> 16;
    return (u16)r;
}
__device__ __forceinline__ float bf2f(u16 v) {
    union { unsigned u; float f; } x; x.u = ((unsigned)v) << 16;
    return x.f;
}

__device__ __forceinline__ void gload16(const void* g, void* l) {
    __builtin_amdgcn_global_load_lds(
        (const __attribute__((address_space(1))) unsigned int*)(uintptr_t)g,
        (__attribute__((address_space(3))) unsigned int*)(uintptr_t)l,
        16, 0, 0);
}

__device__ __forceinline__ void bar_sync() {
    asm volatile("s_waitcnt vmcnt(0)" ::: "memory");
    __builtin_amdgcn_s_barrier();
    asm volatile("" ::: "memory");
}

// rope rotate helper: v at column col (pair = lane^1), i = (col>>1)%384
__device__ __forceinline__ float rope_rot(float v, long row, long col, int lane,
                                          const float2* __restrict__ tab) {
    float vp = __shfl_xor(v, 1, 64);
    int s = (int)(row & (S_ - 1));
    int ii = ((int)col >> 1) % 384;
    float2 f = tab[(long)s * 384 + ii];
    return (lane & 1) ? (vp * f.y + v * f.x) : (v * f.x - vp * f.y);
}

// ---------------------------------------------------------------------------
// 128x128 2-phase kernel. BIAS: 0 none, 1 per-col, 2 per-row.
#define BK 32

template<int OBF, int RELU, int BIAS, int ROPE>
__global__ __launch_bounds__(256) void mgemm(
    const u16* __restrict__ A, const u16* __restrict__ B, void* __restrict__ Cv,
    const float* __restrict__ bias, const float2* __restrict__ tab,
    float alpha, int M, int N, int K,
    int lda, int ldb, int ldc,
    long sA, long sB, long sC)
{
    __shared__ u16 As[2][128 * BK];
    __shared__ u16 Bs[2][128 * BK];

    const int tid  = threadIdx.x;
    const int lane = tid & 63;
    const int wid  = tid >> 6;
    const int wr   = (wid >> 1) * 64;
    const int wc   = (wid & 1) * 64;
    const int lr   = lane & 15;
    const int kg   = lane >> 4;

    const long rowBase = (long)blockIdx.y * 128;
    const long colBase = (long)blockIdx.x * 128;

    const u16* Ab = A + (long)blockIdx.z * sA;
    const u16* Bb = B + (long)blockIdx.z * sB;

    const int c0 = tid, c1 = tid + 256;
    const int ar0 = c0 >> 2, ac0 = (c0 & 3) ^ ((ar0 >> 1) & 3);
    const int ar1 = c1 >> 2, ac1 = (c1 & 3) ^ ((ar1 >> 1) & 3);

    const u16* pa0 = Ab + (rowBase + ar0) * (long)lda + ac0 * 8;
    const u16* pa1 = Ab + (rowBase + ar1) * (long)lda + ac1 * 8;
    const u16* pb0 = Bb + (colBase + ar0) * (long)ldb + ac0 * 8;
    const u16* pb1 = Bb + (colBase + ar1) * (long)ldb + ac1 * 8;

    int aoff[4], boff[4];
    #pragma unroll
    for (int m = 0; m < 4; ++m) {
        int r = wr + m * 16 + lr;
        aoff[m] = r * 32 + ((kg ^ ((r >> 1) & 3)) << 3);
        int c = wc + m * 16 + lr;
        boff[m] = c * 32 + ((kg ^ ((c >> 1) & 3)) << 3);
    }

    floatx4 acc[4][4];
    #pragma unroll
    for (int m = 0; m < 4; ++m)
        #pragma unroll
        for (int n = 0; n < 4; ++n)
            acc[m][n] = (floatx4)0.f;

    auto stage = [&](int buf, int k0) {
        gload16(pa0 + k0, &As[buf][c0 * 8]);
        gload16(pa1 + k0, &As[buf][c1 * 8]);
        gload16(pb0 + k0, &Bs[buf][c0 * 8]);
        gload16(pb1 + k0, &Bs[buf][c1 * 8]);
    };

    const int NT = K / BK;
    stage(0, 0);
    bar_sync();

    for (int t = 0; t < NT; ++t) {
        const int cur = t & 1;
        if (t + 1 < NT) stage(cur ^ 1, (t + 1) * BK);

        bf16x8 af[4], bfr[4];
        #pragma unroll
        for (int m = 0; m < 4; ++m) af[m]  = *(const bf16x8*)(&As[cur][aoff[m]]);
        #pragma unroll
        for (int n = 0; n < 4; ++n) bfr[n] = *(const bf16x8*)(&Bs[cur][boff[n]]);
        #pragma unroll
        for (int m = 0; m < 4; ++m)
            #pragma unroll
            for (int n = 0; n < 4; ++n)
                acc[m][n] = __builtin_amdgcn_mfma_f32_16x16x32_bf16(
                                af[m], bfr[n], acc[m][n], 0, 0, 0);

        if (t + 1 < NT) bar_sync();
    }

    const long col0 = colBase + wc + lr;
    const long row0 = rowBase + wr + kg * 4;
    #pragma unroll
    for (int n = 0; n < 4; ++n) {
        long col = col0 + n * 16;
        float bvc = (BIAS == 1) ? bias[col] : 0.f;
        #pragma unroll
        for (int m = 0; m < 4; ++m)
            #pragma unroll
            for (int j = 0; j < 4; ++j) {
                long row = row0 + m * 16 + j;
                float v = acc[m][n][j] * alpha + bvc;
                if (BIAS == 2) v += bias[row];
                if (ROPE) v = rope_rot(v, row, col, lane, tab);
                if (RELU) v = fmaxf(v, 0.f);
                if (OBF) ((u16*)Cv + (long)blockIdx.z * sC)[row * (long)ldc + col] = f2bf(v);
                else     ((float*)Cv + (long)blockIdx.z * sC)[row * (long)ldc + col] = v;
            }
    }
}

// ---------------------------------------------------------------------------
// 64x128 2-phase kernel (for N=768-class GEMMs).
template<int OBF, int RELU, int BIAS, int ROPE>
__global__ __launch_bounds__(256) void mgemm64(
    const u16* __restrict__ A, const u16* __restrict__ B, void* __restrict__ Cv,
    const float* __restrict__ bias, const float2* __restrict__ tab,
    float alpha, int M, int N, int K,
    int lda, int ldb, int ldc,
    long sA, long sB, long sC)
{
    __shared__ u16 As[2][64 * BK];
    __shared__ u16 Bs[2][128 * BK];

    const int tid  = threadIdx.x;
    const int lane = tid & 63;
    const int wid  = tid >> 6;          // 0..3, wave owns 64M x 32N
    const int lr   = lane & 15;
    const int kg   = lane >> 4;

    const long rowBase = (long)blockIdx.y * 64;
    const long colBase = (long)blockIdx.x * 128;

    const u16* Ab = A + (long)blockIdx.z * sA;
    const u16* Bb = B + (long)blockIdx.z * sB;

    const int ra = tid >> 2, cha = (tid & 3) ^ ((ra >> 1) & 3);
    const int c0 = tid, c1 = tid + 256;
    const int rb0 = c0 >> 2, chb0 = (c0 & 3) ^ ((rb0 >> 1) & 3);
    const int rb1 = c1 >> 2, chb1 = (c1 & 3) ^ ((rb1 >> 1) & 3);

    const u16* pa  = Ab + (rowBase + ra)  * (long)lda + cha  * 8;
    const u16* pb0 = Bb + (colBase + rb0) * (long)ldb + chb0 * 8;
    const u16* pb1 = Bb + (colBase + rb1) * (long)ldb + chb1 * 8;

    int aoff[4], boff[2];
    #pragma unroll
    for (int m = 0; m < 4; ++m) {
        int r = m * 16 + lr;
        aoff[m] = r * 32 + ((kg ^ ((r >> 1) & 3)) << 3);
    }
    #pragma unroll
    for (int n = 0; n < 2; ++n) {
        int c = wid * 32 + n * 16 + lr;
        boff[n] = c * 32 + ((kg ^ ((c >> 1) & 3)) << 3);
    }

    floatx4 acc[4][2];
    #pragma unroll
    for (int m = 0; m < 4; ++m)
        #pragma unroll
        for (int n = 0; n < 2; ++n)
            acc[m][n] = (floatx4)0.f;

    auto stage = [&](int buf, int k0) {
        gload16(pa  + k0, &As[buf][tid * 8]);
        gload16(pb0 + k0, &Bs[buf][c0 * 8]);
        gload16(pb1 + k0, &Bs[buf][c1 * 8]);
    };

    const int NT = K / BK;
    stage(0, 0);
    bar_sync();

    for (int t = 0; t < NT; ++t) {
        const int cur = t & 1;
        if (t + 1 < NT) stage(cur ^ 1, (t + 1) * BK);

        bf16x8 af[4], bfr[2];
        #pragma unroll
        for (int m = 0; m < 4; ++m) af[m]  = *(const bf16x8*)(&As[cur][aoff[m]]);
        #pragma unroll
        for (int n = 0; n < 2; ++n) bfr[n] = *(const bf16x8*)(&Bs[cur][boff[n]]);
        #pragma unroll
        for (int m = 0; m < 4; ++m)
            #pragma unroll
            for (int n = 0; n < 2; ++n)
                acc[m][n] = __builtin_amdgcn_mfma_f32_16x16x32_bf16(
                                af[m], bfr[n], acc[m][n], 0, 0, 0);

        if (t + 1 < NT) bar_sync();
    }

    const long col0 = colBase + wid * 32 + lr;
    const long row0 = rowBase + kg * 4;
    #pragma unroll
    for (int n = 0; n < 2; ++n) {
        long col = col0 + n * 16;
        float bvc = (BIAS == 1) ? bias[col] : 0.f;
        #pragma unroll
        for (int m = 0; m < 4; ++m)
            #pragma unroll
            for (int j = 0; j < 4; ++j) {
                long row = row0 + m * 16 + j;
                float v = acc[m][n][j] * alpha + bvc;
                if (BIAS == 2) v += bias[row];
                if (ROPE) v = rope_rot(v, row, col, lane, tab);
                if (RELU) v = fmaxf(v, 0.f);
                if (OBF) ((u16*)Cv + (long)blockIdx.z * sC)[row * (long)ldc + col] = f2bf(v);
                else     ((float*)Cv + (long)blockIdx.z * sC)[row * (long)ldc + col] = v;
            }
    }
}

// ---------------------------------------------------------------------------
// 256x256 8-wave phase-split pipelined GEMM — unembed only (1024 blocks).
template<int OBF, int RELU, int BIAS>
__global__ __launch_bounds__(512, 2) void mgemm8(
    const u16* __restrict__ A, const u16* __restrict__ B, void* __restrict__ Cv,
    const float* __restrict__ bias, float alpha, int M, int N, int K,
    int lda, int ldb, int ldc)
{
    __shared__ u16 As[3][256 * 32];
    __shared__ u16 Bs[3][256 * 32];

    const int tid  = threadIdx.x;
    const int lane = tid & 63;
    const int wid  = tid >> 6;
    const int wm   = wid >> 2;
    const int wn   = wid & 3;
    const int lr   = lane & 15;
    const int kg   = lane >> 4;

    const long rowBase = (long)blockIdx.y * 256;
    const long colBase = (long)blockIdx.x * 256;

    const int c0 = tid, c1 = tid + 512;
    const int r0 = c0 >> 2, ch0 = (c0 & 3) ^ ((r0 >> 1) & 3);
    const int r1 = c1 >> 2, ch1 = (c1 & 3) ^ ((r1 >> 1) & 3);

    const u16* pa0 = A + (rowBase + r0) * (long)lda + ch0 * 8;
    const u16* pa1 = A + (rowBase + r1) * (long)lda + ch1 * 8;
    const u16* pb0 = B + (colBase + r0) * (long)ldb + ch0 * 8;
    const u16* pb1 = B + (colBase + r1) * (long)ldb + ch1 * 8;

    int aoff[8], boff[4];
    #pragma unroll
    for (int mi = 0; mi < 8; ++mi) {
        int r = wm * 128 + mi * 16 + lr;
        aoff[mi] = r * 32 + ((kg ^ ((r >> 1) & 3)) << 3);
    }
    #pragma unroll
    for (int ni = 0; ni < 4; ++ni) {
        int c = wn * 64 + ni * 16 + lr;
        boff[ni] = c * 32 + ((kg ^ ((c >> 1) & 3)) << 3);
    }

    floatx4 acc[8][4];
    #pragma unroll
    for (int mi = 0; mi < 8; ++mi)
        #pragma unroll
        for (int ni = 0; ni < 4; ++ni)
            acc[mi][ni] = (floatx4)0.f;

    auto stageA = [&](int buf, int kt) {
        gload16(pa0 + (long)kt * 32, &As[buf][c0 * 8]);
        gload16(pa1 + (long)kt * 32, &As[buf][c1 * 8]);
    };
    auto stageB = [&](int buf, int kt) {
        gload16(pb0 + (long)kt * 32, &Bs[buf][c0 * 8]);
        gload16(pb1 + (long)kt * 32, &Bs[buf][c1 * 8]);
    };

    const int NT = K / 32;
    stageA(0, 0); stageB(0, 0);
    stageA(1, 1); stageB(1, 1);
    asm volatile("s_waitcnt vmcnt(4)" ::: "memory");
    __builtin_amdgcn_sched_barrier(0);
    __builtin_amdgcn_s_barrier();

    int b0 = 0, b1 = 1, b2 = 2;
    for (int t = 0; t < NT; ++t) {
        bf16x8 afr[4], bfr[4];
        if (t + 2 < NT) stageA(b2, t + 2);
        #pragma unroll
        for (int mi = 0; mi < 4; ++mi) afr[mi] = *(const bf16x8*)(&As[b0][aoff[mi]]);
        #pragma unroll
        for (int ni = 0; ni < 4; ++ni) bfr[ni] = *(const bf16x8*)(&Bs[b0][boff[ni]]);
        __builtin_amdgcn_s_barrier();
        asm volatile("s_waitcnt lgkmcnt(0)" ::: "memory");
        __builtin_amdgcn_sched_barrier(0);
        __builtin_amdgcn_s_setprio(1);
        #pragma unroll
        for (int mi = 0; mi < 4; ++mi)
            #pragma unroll
            for (int ni = 0; ni < 4; ++ni)
                acc[mi][ni] = __builtin_amdgcn_mfma_f32_16x16x32_bf16(
                                  afr[mi], bfr[ni], acc[mi][ni], 0, 0, 0);
        __builtin_amdgcn_s_setprio(0);
        __builtin_amdgcn_sched_barrier(0);
        __builtin_amdgcn_s_barrier();
        if (t + 2 < NT) stageB(b2, t + 2);
        #pragma unroll
        for (int mi = 0; mi < 4; ++mi) afr[mi] = *(const bf16x8*)(&As[b0][aoff[4 + mi]]);
        __builtin_amdgcn_s_barrier();
        asm volatile("s_waitcnt lgkmcnt(0)" ::: "memory");
        __builtin_amdgcn_sched_barrier(0);
        __builtin_amdgcn_s_setprio(1);
        #pragma unroll
        for (int mi = 0; mi < 4; ++mi)
            #pragma unroll
            for (int ni = 0; ni < 4; ++ni)
                acc[4 + mi][ni] = __builtin_amdgcn_mfma_f32_16x16x32_bf16(
                                      afr[mi], bfr[ni], acc[4 + mi][ni], 0, 0, 0);
        __builtin_amdgcn_s_setprio(0);
        __builtin_amdgcn_sched_barrier(0);
        if (t + 2 < NT) { asm volatile("s_waitcnt vmcnt(4)" ::: "memory"); }
        else            { asm volatile("s_waitcnt vmcnt(0)" ::: "memory"); }
        __builtin_amdgcn_sched_barrier(0);
        __builtin_amdgcn_s_barrier();
        int tb = b0; b0 = b1; b1 = b2; b2 = tb;
    }

    const long col0 = colBase + wn * 64 + lr;
    const long row0 = rowBase + wm * 128 + kg * 4;
    #pragma unroll
    for (int ni = 0; ni < 4; ++ni) {
        long col = col0 + ni * 16;
        float bv = BIAS ? bias[col] : 0.f;
        #pragma unroll
        for (int mi = 0; mi < 8; ++mi)
            #pragma unroll
            for (int j = 0; j < 4; ++j) {
                float v = acc[mi][ni][j] * alpha + bv;
                if (RELU) v = fmaxf(v, 0.f);
                if (OBF) ((u16*)Cv)[(row0 + mi * 16 + j) * (long)ldc + col] = f2bf(v);
                else     ((float*)Cv)[(row0 + mi * 16 + j) * (long)ldc + col] = v;
            }
    }
}

// ---------------------------------------------------------------------------
// fp32 [R][C] -> bf16 [C][R] weight transpose-convert.
__global__ __launch_bounds__(256) void tcvt(
    const float* __restrict__ in, u16* __restrict__ out,
    int ldIn, int ldOut, long sIn, long sOut)
{
    __shared__ u16 t[32][33];
    const int tx = threadIdx.x & 31, ty = threadIdx.x >> 5;
    const long r0 = (long)blockIdx.y * 32, c0 = (long)blockIdx.x * 32;
    const float* ib = in + (long)blockIdx.z * sIn;
    u16* ob = out + (long)blockIdx.z * sOut;
    #pragma unroll
    for (int j = 0; j < 4; ++j) {
        int r = ty + j * 8;
        t[r][tx] = f2bf(ib[(r0 + r) * (long)ldIn + c0 + tx]);
    }
    __syncthreads();
    #pragma unroll
    for (int j = 0; j < 4; ++j) {
        int c = ty + j * 8;
        ob[(c0 + c) * (long)ldOut + r0 + tx] = t[tx][c];
    }
}

// ---------------------------------------------------------------------------
// Embedding gather -> bf16 embeds.
__global__ __launch_bounds__(256) void gather_kernel(
    const int* __restrict__ seq, const float* __restrict__ embed,
    u16* __restrict__ xb)
{
    int t = blockIdx.x;
    int tok = seq[t];
    const float* src = embed + (long)tok * E_;
    long base = (long)t * E_;
    #pragma unroll
    for (int j = 0; j < 3; ++j) {
        int i = threadIdx.x + j * 256;
        xb[base + i] = f2bf(src[i]);
    }
}

__global__ __launch_bounds__(256) void copy_kernel(
    const float4* __restrict__ src, float4* __restrict__ dst, long n)
{
    long i = (long)blockIdx.x * blockDim.x + threadIdx.x;
    if (i < n) dst[i] = src[i];
}

// ---------------------------------------------------------------------------
__global__ __launch_bounds__(384) void rope_tab_kernel(float2* __restrict__ tab)
{
    int s = blockIdx.x;
    int i = threadIdx.x;
    float inv = expf(-(float)(2 * i) * (9.210340371976184f / (float)E_));
    float ang = (float)s * inv;
    float sn, cs;
    sincosf(ang, &sn, &cs);
    tab[(long)s * 384 + i] = make_float2(cs, sn);
}

// ---------------------------------------------------------------------------
// In-place softmax on bf16 scores (scale pre-applied). One block per row.
__global__ __launch_bounds__(256) void softmax_kernel(
    u16* __restrict__ P, int causal)
{
    __shared__ float sred[4];
    int row = blockIdx.x;
    int s = row & (S_ - 1);
    u16* p = P + (long)row * S_;
    int tid = threadIdx.x;
    int lane = tid & 63, wid = tid >> 6;

    u16x4 raw = *(const u16x4*)(p + tid * 4);
    float v[4];
    float mx = -INFINITY;
    #pragma unroll
    for (int j = 0; j < 4; ++j) {
        int col = tid * 4 + j;
        float val = bf2f(raw[j]);
        if (causal && col > s) val = -INFINITY;
        v[j] = val;
        mx = fmaxf(mx, val);
    }
    #pragma unroll
    for (int off = 1; off < 64; off <<= 1)
        mx = fmaxf(mx, __shfl_xor(mx, off, 64));
    if (lane == 0) sred[wid] = mx;
    __syncthreads();
    mx = fmaxf(fmaxf(sred[0], sred[1]), fmaxf(sred[2], sred[3]));
    __syncthreads();

    float sum = 0.f;
    #pragma unroll
    for (int j = 0; j < 4; ++j) {
        v[j] = __expf(v[j] - mx);
        sum += v[j];
    }
    #pragma unroll
    for (int off = 1; off < 64; off <<= 1)
        sum += __shfl_xor(sum, off, 64);
    if (lane == 0) sred[wid] = sum;
    __syncthreads();
    sum = sred[0] + sred[1] + sred[2] + sred[3];

    float invs = 1.f / sum;
    u16x4 o;
    #pragma unroll
    for (int j = 0; j < 4; ++j) o[j] = f2bf(v[j] * invs);
    *(u16x4*)(p + tid * 4) = o;
}

// ---------------------------------------------------------------------------
// xout = LN(xin + hin)*g + b, all bf16 (fp32 stats). One WAVE per row.
__global__ __launch_bounds__(256) void add_ln_kernel(
    const u16* __restrict__ xin, const u16* __restrict__ hin,
    const float* __restrict__ gb, u16* __restrict__ xout)
{
    int row = blockIdx.x * 4 + (threadIdx.x >> 6);
    int lane = threadIdx.x & 63;
    const u16x4* xr = (const u16x4*)(xin + (long)row * E_);
    const u16x4* hr = (const u16x4*)(hin + (long)row * E_);

    float4 v[3];
    float sum = 0.f, sq = 0.f;
    #pragma unroll
    for (int l = 0; l < 3; ++l) {
        int idx = l * 64 + lane;
        u16x4 a = xr[idx];
        u16x4 b = hr[idx];
        v[l].x = bf2f(a[0]) + bf2f(b[0]);
        v[l].y = bf2f(a[1]) + bf2f(b[1]);
        v[l].z = bf2f(a[2]) + bf2f(b[2]);
        v[l].w = bf2f(a[3]) + bf2f(b[3]);
        sum += v[l].x + v[l].y + v[l].z + v[l].w;
        sq  += v[l].x*v[l].x + v[l].y*v[l].y + v[l].z*v[l].z + v[l].w*v[l].w;
    }
    #pragma unroll
    for (int off = 1; off < 64; off <<= 1) {
        sum += __shfl_xor(sum, off, 64);
        sq  += __shfl_xor(sq,  off, 64);
    }

    float mu  = sum * (1.f / E_);
    float var = sq * (1.f / E_) - mu * mu;
    float inv = rsqrtf(var + 1e-5f);

    const float4* g4 = (const float4*)gb;
    const float4* b4 = (const float4*)(gb + E_);
    u16x4* xo = (u16x4*)(xout + (long)row * E_);
    #pragma unroll
    for (int l = 0; l < 3; ++l) {
        int idx = l * 64 + lane;
        float4 g = g4[idx], bb = b4[idx];
        u16x4 ob;
        ob[0] = f2bf((v[l].x - mu) * inv * g.x + bb.x);
        ob[1] = f2bf((v[l].y - mu) * inv * g.y + bb.y);
        ob[2] = f2bf((v[l].z - mu) * inv * g.z + bb.z);
        ob[3] = f2bf((v[l].w - mu) * inv * g.w + bb.w);
        xo[idx] = ob;
    }
}

// ---------------------------------------------------------------------------
extern "C" void kernel_launch(void* const* d_in, const int* in_sizes, int n_in,
                              void* d_out, int out_size, void* d_ws, size_t ws_size,
                              hipStream_t stream) {
    const int*   seq       = (const int*)d_in[0];
    const float* embed     = (const float*)d_in[2];
    const float* enc_qkv_w = (const float*)d_in[3];
    const float* enc_qkv_b = (const float*)d_in[4];
    const float* enc_ln    = (const float*)d_in[5];
    const float* enc_w1    = (const float*)d_in[6];
    const float* enc_b1    = (const float*)d_in[7];
    const float* enc_w2    = (const float*)d_in[8];
    const float* enc_b2    = (const float*)d_in[9];
    const float* dec_qkv_w = (const float*)d_in[10];
    const float* dec_qkv_b = (const float*)d_in[11];
    const float* dec_ln    = (const float*)d_in[12];
    const float* dec_w1    = (const float*)d_in[13];
    const float* dec_b1    = (const float*)d_in[14];
    const float* dec_w2    = (const float*)d_in[15];
    const float* dec_b2    = (const float*)d_in[16];
    const float* unembed   = (const float*)d_in[17];

    const long TE  = (long)T_TOK * E_;
    const long TH  = (long)T_TOK * H_;
    const long SE  = (long)S_ * E_;
    const long SS  = (long)S_ * S_;
    const long SS4 = (long)B_ * SS;
    const long EE  = (long)E_ * E_;
    const long EH  = (long)E_ * H_;
    const long VE  = (long)V_ * E_;
    const long TQK = (long)T_TOK * 1536;
    const long SQK = (long)S_ * 1536;
    const long TABF = (long)S_ * 384 * 2;   // floats

    float*  ws    = (float*)d_ws;
    float2* f_tab = (float2*)ws;

    u16* u_emb = (u16*)(ws + TABF);     // TE
    u16* u_x   = u_emb + TE;            // TE  (bf16 residual state)
    u16* u_h   = u_x + TE;              // TE  (attn/MLP output, bf16)
    u16* u_enc = u_h + TE;              // 5*TE
    u16* u_qk  = u_enc + 5 * TE;        // TQK = 2*TE
    u16* u_vT  = u_qk + TQK;            // TE  ([768][4096])
    u16* u_hid = u_vT + TE;             // TH
    u16* u_P   = u_hid + TH;            // SS4
    u16* u_w   = u_P + SS4;

    const long WTOT = 45 * EE + 20 * EH + VE;
    size_t need_persist = (size_t)((char*)(u_w + WTOT) - (char*)d_ws);
    bool persist = ws_size >= need_persist;

    u16* pw_eqkv = u_w;
    u16* pw_dqkv = pw_eqkv + 15 * EE;
    u16* pw_ew1  = pw_dqkv + 30 * EE;
    u16* pw_ew2  = pw_ew1 + 5 * EH;
    u16* pw_dw1  = pw_ew2 + 5 * EH;
    u16* pw_dw2  = pw_dw1 + 5 * EH;
    u16* pw_un   = pw_dw2 + 5 * EH;

    const float SCALE = 0.03608439182435161f; // 1/sqrt(768)

    auto T = [&](const float* in, u16* out, int R, int C, int z) {
        dim3 g(C / 32, R / 32, z);
        tcvt<<<g, 256, 0, stream>>>(in, out, C, R, (long)R * C, (long)R * C);
    };
    auto WTz = [&](const float* w, int R, int C, int z, u16* pp) -> const u16* {
        if (persist) return pp;
        T(w, u_w, R, C, z);
        return u_w;
    };

    if (persist) {
        T(enc_qkv_w, pw_eqkv, E_, E_, 15);
        T(dec_qkv_w, pw_dqkv, E_, E_, 30);
        T(enc_w1, pw_ew1, E_, H_, L_);
        T(enc_w2, pw_ew2, H_, E_, L_);
        T(dec_w1, pw_dw1, E_, H_, L_);
        T(dec_w2, pw_dw2, H_, E_, L_);
        T(unembed, pw_un, E_, V_, 1);
    }

    rope_tab_kernel<<<S_, 384, 0, stream>>>(f_tab);
    gather_kernel<<<T_TOK, 256, 0, stream>>>(seq, embed, u_emb);

    // --- per-op launchers -------------------------------------------------
    auto qk_rope = [&](const u16* X, const u16* W, const float* bias) {
        dim3 g(1536 / 128, T_TOK / 128, 1);
        mgemm<1,0,1,1><<<g,256,0,stream>>>(X, W, u_qk, bias, f_tab, 1.f,
            T_TOK, 1536, E_, E_, E_, 1536, 0, 0, 0);
    };
    auto proj_rope64 = [&](const u16* X, const u16* W, u16* dst, const float* bias) {
        dim3 g(768 / 128, T_TOK / 64, 1);
        mgemm64<1,0,1,1><<<g,256,0,stream>>>(X, W, dst, bias, f_tab, 1.f,
            T_TOK, 768, E_, E_, E_, 1536, 0, 0, 0);
    };
    // V^T = Wv^T @ X^T  (M=768 d-rows, N=4096 tokens), row-bias
    auto vT_gemm = [&](const u16* Wv, const u16* X, const float* biasrow) {
        dim3 g(T_TOK / 128, 768 / 64, 1);
        mgemm64<1,0,2,0><<<g,256,0,stream>>>(Wv, X, u_vT, biasrow, nullptr, 1.f,
            768, T_TOK, E_, E_, E_, T_TOK, 0, 0, 0);
    };
    auto qkt = [&]() {
        dim3 g(S_ / 128, S_ / 128, B_);
        mgemm<1,0,0,0><<<g,256,0,stream>>>(u_qk, u_qk + 768, u_P, nullptr, nullptr,
            SCALE, S_, S_, E_, 1536, 1536, S_, SQK, SQK, SS);
    };
    auto pv = [&]() {
        dim3 g(E_ / 128, S_ / 64, B_);
        mgemm64<1,0,0,0><<<g,256,0,stream>>>(u_P, u_vT, u_h, nullptr, nullptr, 1.f,
            S_, E_, S_, S_, T_TOK, E_, SS, 1024, SE);
    };
    auto mlp1 = [&](const u16* X, const u16* W, const float* b1) {
        dim3 g(H_ / 128, T_TOK / 128, 1);
        mgemm<1,1,1,0><<<g,256,0,stream>>>(X, W, u_hid, b1, nullptr, 1.f,
            T_TOK, H_, E_, E_, E_, H_, 0, 0, 0);
    };
    auto mlp2 = [&](const u16* W, const float* b2) {
        dim3 g(E_ / 128, T_TOK / 64, 1);
        mgemm64<1,1,1,0><<<g,256,0,stream>>>(u_hid, W, u_h, b2, nullptr, 1.f,
            T_TOK, E_, H_, H_, H_, E_, 0, 0, 0);
    };
    auto lnz = [&](const u16* xin, const float* gb, u16* xbdst) {
        add_ln_kernel<<<T_TOK / 4, 256, 0, stream>>>(xin, u_h, gb, xbdst);
    };
    auto sm = [&](int causal) {
        softmax_kernel<<<T_TOK, 256, 0, stream>>>(u_P, causal);
    };

    // ------------------------ encoder ------------------------
    for (int i = 0; i < L_; ++i) {
        const u16* xsrc = (i == 0) ? u_emb : u_enc + (long)(i - 1) * TE;
        const float* bb = enc_qkv_b + (long)i * 3 * E_;
        qk_rope(xsrc, WTz(enc_qkv_w + (long)i * 3 * EE, E_, E_, 2,
                          pw_eqkv + (long)i * 3 * EE), bb);
        vT_gemm(WTz(enc_qkv_w + ((long)i * 3 + 2) * EE, E_, E_, 1,
                    pw_eqkv + ((long)i * 3 + 2) * EE), xsrc, bb + 2 * E_);
        qkt();
        sm(0);
        pv();
        lnz(xsrc, enc_ln + (2L * i + 0) * 2 * E_, u_x);
        mlp1(u_x, WTz(enc_w1 + (long)i * EH, E_, H_, 1, pw_ew1 + (long)i * EH),
             enc_b1 + (long)i * H_);
        mlp2(WTz(enc_w2 + (long)i * EH, H_, E_, 1, pw_ew2 + (long)i * EH),
             enc_b2 + (long)i * E_);
        lnz(u_x, enc_ln + (2L * i + 1) * 2 * E_, u_enc + (long)i * TE);
    }

    // ------------------------ decoder ------------------------
    copy_kernel<<<(TE / 8 + 255) / 256, 256, 0, stream>>>(
        (const float4*)u_emb, (float4*)u_x, TE / 8);
    for (int i = 0; i < L_; ++i) {
        const u16* kv_bf = u_enc + (long)i * TE;
        const float* bb = dec_qkv_b + (long)i * 6 * E_;

        // self-attention (causal)
        qk_rope(u_x, WTz(dec_qkv_w + (long)i * 6 * EE, E_, E_, 2,
                         pw_dqkv + (long)i * 6 * EE), bb);
        vT_gemm(WTz(dec_qkv_w + ((long)i * 6 + 2) * EE, E_, E_, 1,
                    pw_dqkv + ((long)i * 6 + 2) * EE), u_x, bb + 2 * E_);
        qkt();
        sm(1);
        pv();
        lnz(u_x, dec_ln + (3L * i + 0) * 2 * E_, u_x);

        // cross-attention
        proj_rope64(u_x, WTz(dec_qkv_w + ((long)i * 6 + 3) * EE, E_, E_, 1,
                             pw_dqkv + ((long)i * 6 + 3) * EE), u_qk, bb + 3 * E_);
        proj_rope64(kv_bf, WTz(dec_qkv_w + ((long)i * 6 + 4) * EE, E_, E_, 1,
                               pw_dqkv + ((long)i * 6 + 4) * EE), u_qk + 768, bb + 4 * E_);
        vT_gemm(WTz(dec_qkv_w + ((long)i * 6 + 5) * EE, E_, E_, 1,
                    pw_dqkv + ((long)i * 6 + 5) * EE), kv_bf, bb + 5 * E_);
        qkt();
        sm(0);
        pv();
        lnz(u_x, dec_ln + (3L * i + 1) * 2 * E_, u_x);

        // MLP
        mlp1(u_x, WTz(dec_w1 + (long)i * EH, E_, H_, 1, pw_dw1 + (long)i * EH),
             dec_b1 + (long)i * H_);
        mlp2(WTz(dec_w2 + (long)i * EH, H_, E_, 1, pw_dw2 + (long)i * EH),
             dec_b2 + (long)i * E_);
        lnz(u_x, dec_ln + (3L * i + 2) * 2 * E_, u_x);
    }

    // ------------------------ unembed ------------------------
    {
        dim3 g(V_ / 256, T_TOK / 256, 1);
        mgemm8<0,0,0><<<g,512,0,stream>>>(u_x, WTz(unembed, E_, V_, 1, pw_un),
            d_out, nullptr, 1.f, T_TOK, V_, E_, E_, E_, V_);
    }
}